// Round 6
// baseline (32000.266 us; speedup 1.0000x reference)
//
#include <hip/hip_runtime.h>
#include <math.h>

#define BS     16
#define NB     4
#define BB     64      // BS*NB
#define DD     512
#define VV     32000
#define TSTEPS 16
#define EOSTOK 2
#define NEGF   (-1e32f)

__device__ __forceinline__ bool better(float av, int ai, float bv, int bi_) {
    return (av > bv) || (av == bv && ai < bi_);
}

// ---------------------------------------------------------------- init
__global__ void init_kernel(const int* __restrict__ inputs,
                            const float* __restrict__ h0, const float* __restrict__ c0,
                            double* __restrict__ h0c, double* __restrict__ c0c,
                            double* __restrict__ h1c, double* __restrict__ c1c,
                            int* __restrict__ tokens, int* __restrict__ pidx,
                            int* __restrict__ fin, float* __restrict__ lp,
                            int* __restrict__ bo)
{
    int tid = blockIdx.x * blockDim.x + threadIdx.x;
    int total = BB * DD;
    for (int i = tid; i < total; i += gridDim.x * blockDim.x) {
        int b = i / DD;
        int d = i % DD;
        int src0 = 0 * BS * DD + (b >> 2) * DD + d;
        int src1 = 1 * BS * DD + (b >> 2) * DD + d;
        h0c[i] = (double)h0[src0];
        c0c[i] = (double)c0[src0];
        h1c[i] = (double)h0[src1];
        c1c[i] = (double)c0[src1];
    }
    if (tid < BB) {
        tokens[tid] = inputs[tid >> 2];
        pidx[tid]   = tid;
        fin[tid]    = 0;
        lp[tid]     = 0.0f;
        bo[0 * BB + tid] = inputs[tid >> 2];
        for (int r = 1; r <= TSTEPS; r++) bo[r * BB + tid] = 0;
    }
}

// ---------------------------------------------------------------- explicit gather
__global__ void gather_kernel(const float* __restrict__ emb,
                              const int* __restrict__ tokens, const int* __restrict__ pidx,
                              const double* __restrict__ h0c, const double* __restrict__ c0c,
                              const double* __restrict__ h1c, const double* __restrict__ c1c,
                              double* __restrict__ xg,
                              double* __restrict__ hg0, double* __restrict__ cg0,
                              double* __restrict__ hg1, double* __restrict__ cg1)
{
    int b = blockIdx.x;
    int tok = tokens[b];
    int p   = pidx[b];
    for (int d = threadIdx.x; d < DD; d += blockDim.x) {
        xg[b * DD + d]  = (double)emb[(size_t)tok * DD + d];
        hg0[b * DD + d] = h0c[p * DD + d];
        cg0[b * DD + d] = c0c[p * DD + d];
        hg1[b * DD + d] = h1c[p * DD + d];
        cg1[b * DD + d] = c1c[p * DD + d];
    }
}

// ---------------------------------------------------------------- LSTM layer (fp64 internal, fp32-rounded state)
__global__ __launch_bounds__(512) void lstm_kernel(
    const double* __restrict__ xg, const double* __restrict__ hg,
    const double* __restrict__ cg,
    const float* __restrict__ Wih, const float* __restrict__ Whh,
    const float* __restrict__ bias,
    double* __restrict__ hout, double* __restrict__ cout)
{
    __shared__ double sx[DD];
    __shared__ double sh[DD];
    int b = blockIdx.x;
    int j = threadIdx.x;
    sx[j] = xg[b * DD + j];
    sh[j] = hg[b * DD + j];
    __syncthreads();

    double acc0 = 0.0, acc1 = 0.0, acc2 = 0.0, acc3 = 0.0;
    const float* wi0 = Wih + (size_t)(0 * DD + j) * DD;
    const float* wi1 = Wih + (size_t)(1 * DD + j) * DD;
    const float* wi2 = Wih + (size_t)(2 * DD + j) * DD;
    const float* wi3 = Wih + (size_t)(3 * DD + j) * DD;
    const float* wh0 = Whh + (size_t)(0 * DD + j) * DD;
    const float* wh1 = Whh + (size_t)(1 * DD + j) * DD;
    const float* wh2 = Whh + (size_t)(2 * DD + j) * DD;
    const float* wh3 = Whh + (size_t)(3 * DD + j) * DD;
    for (int k = 0; k < DD; k++) {
        double xv = sx[k];
        double hv = sh[k];
        acc0 = fma(xv, (double)wi0[k], acc0);
        acc1 = fma(xv, (double)wi1[k], acc1);
        acc2 = fma(xv, (double)wi2[k], acc2);
        acc3 = fma(xv, (double)wi3[k], acc3);
        acc0 = fma(hv, (double)wh0[k], acc0);
        acc1 = fma(hv, (double)wh1[k], acc1);
        acc2 = fma(hv, (double)wh2[k], acc2);
        acc3 = fma(hv, (double)wh3[k], acc3);
    }

    double zi = acc0 + (double)bias[0 * DD + j];
    double zf = acc1 + (double)bias[1 * DD + j];
    double zg = acc2 + (double)bias[2 * DD + j];
    double zo = acc3 + (double)bias[3 * DD + j];
    double si = 1.0 / (1.0 + exp(-zi));
    double sf = 1.0 / (1.0 + exp(-zf));
    double so = 1.0 / (1.0 + exp(-zo));
    double cn = sf * cg[b * DD + j] + si * tanh(zg);
    double hn = so * tanh(cn);
    // round state to fp32 at the step boundary, mirroring the reference's fp32 storage
    hout[b * DD + j] = (double)(float)hn;
    cout[b * DD + j] = (double)(float)cn;
}

// ---------------------------------------------------------------- projection GEMM (fp64 acc, fp32-rounded logits)
__global__ __launch_bounds__(256) void proj_kernel(
    const double* __restrict__ h1, const float* __restrict__ Wp,
    const float* __restrict__ bp, float* __restrict__ outf,
    double* __restrict__ outd)
{
    __shared__ double shd[32][65];
    __shared__ float  swf[32][132];
    int tid = threadIdx.x;
    int v0 = blockIdx.x * 128;
    int tb = (tid >> 4) * 4;
    int tv = (tid & 15) * 8;

    double acc[4][8];
    #pragma unroll
    for (int a = 0; a < 4; a++)
        #pragma unroll
        for (int q = 0; q < 8; q++) acc[a][q] = 0.0;

    for (int ch = 0; ch < 16; ch++) {
        int k0 = ch * 32;
        __syncthreads();
        #pragma unroll
        for (int i = 0; i < 8; i++) {
            int e = tid + i * 256;
            int k = e >> 6;
            int b = e & 63;
            shd[k][b] = h1[b * DD + k0 + k];
        }
        #pragma unroll
        for (int i = 0; i < 16; i++) {
            int e = tid + i * 256;
            int v = e & 127;
            int k = e >> 7;
            swf[k][v] = Wp[(size_t)(k0 + k) * VV + v0 + v];
        }
        __syncthreads();
        #pragma unroll 4
        for (int k = 0; k < 32; k++) {
            double hv0 = shd[k][tb + 0];
            double hv1 = shd[k][tb + 1];
            double hv2 = shd[k][tb + 2];
            double hv3 = shd[k][tb + 3];
            #pragma unroll
            for (int q = 0; q < 8; q++) {
                double wq = (double)swf[k][tv + q];
                acc[0][q] = fma(hv0, wq, acc[0][q]);
                acc[1][q] = fma(hv1, wq, acc[1][q]);
                acc[2][q] = fma(hv2, wq, acc[2][q]);
                acc[3][q] = fma(hv3, wq, acc[3][q]);
            }
        }
    }

    #pragma unroll
    for (int a = 0; a < 4; a++) {
        int brow = tb + a;
        #pragma unroll
        for (int q = 0; q < 8; q++) {
            int v = v0 + tv + q;
            float zf = (float)(acc[a][q] + (double)bp[v]);   // fp32 logit (ref boundary)
            outf[(size_t)brow * VV + v] = zf;
            outd[(size_t)brow * VV + v] = (double)zf;        // fp32 value carried in fp64
        }
    }
}

// ---------------------------------------------------------------- per-row logsumexp (fp64 from fp32 logits)
__global__ __launch_bounds__(256) void lse_kernel(const double* __restrict__ outd,
                                                  double* __restrict__ lse)
{
    int row = blockIdx.x;
    const double* p = outd + (size_t)row * VV;
    int tid = threadIdx.x;
    __shared__ double red[256];

    double m = -1e300;
    for (int i = tid; i < VV; i += 256) m = fmax(m, p[i]);
    red[tid] = m; __syncthreads();
    for (int s = 128; s > 0; s >>= 1) {
        if (tid < s) red[tid] = fmax(red[tid], red[tid + s]);
        __syncthreads();
    }
    m = red[0];
    __syncthreads();

    double sum = 0.0;
    for (int i = tid; i < VV; i += 256) sum += exp(p[i] - m);
    red[tid] = sum; __syncthreads();
    for (int s = 128; s > 0; s >>= 1) {
        if (tid < s) red[tid] += red[tid + s];
        __syncthreads();
    }
    if (tid == 0) lse[row] = m + log(red[0]);
}

// ---------------------------------------------------------------- top-4 per batch (fp32 score grid, index tie-break)
__global__ __launch_bounds__(256) void topk_kernel(
    const double* __restrict__ outd, const double* __restrict__ lse,
    const float* __restrict__ lp, const int* __restrict__ fin,
    float* __restrict__ newlp, int* __restrict__ beams, int step0)
{
    int bi = blockIdx.x;
    int tid = threadIdx.x;
    __shared__ float rv[256];
    __shared__ int   ri[256];
    __shared__ float winv[4];
    __shared__ int   win[4];

    int jmax = step0 ? 1 : NB;

    for (int pass = 0; pass < 4; pass++) {
        float bvv = -3.4e38f;
        int   bii = 0x7fffffff;
        for (int j = 0; j < jmax; j++) {
            int row = bi * NB + j;
            double lse_r = lse[row];
            float  lp_r  = step0 ? 0.0f : lp[row];
            int f        = step0 ? 0    : fin[row];
            const double* base = outd + (size_t)row * VV;
            for (int v = tid; v < VV; v += 256) {
                int idx = j * VV + v;
                bool skip = false;
                for (int q = 0; q < pass; q++) skip = skip || (idx == win[q]);
                if (skip) continue;
                float val;
                if (f) {
                    val = (v == 0) ? lp_r : NEGF;
                } else {
                    float lgp32 = (float)(base[v] - lse_r);       // fp32 log-softmax value
                    val = (float)((double)lp_r + (double)lgp32);  // exact fp32 add
                }
                if (better(val, idx, bvv, bii)) { bvv = val; bii = idx; }
            }
        }
        rv[tid] = bvv; ri[tid] = bii;
        __syncthreads();
        for (int s = 128; s > 0; s >>= 1) {
            if (tid < s) {
                if (better(rv[tid + s], ri[tid + s], rv[tid], ri[tid])) {
                    rv[tid] = rv[tid + s]; ri[tid] = ri[tid + s];
                }
            }
            __syncthreads();
        }
        if (tid == 0) { win[pass] = ri[0]; winv[pass] = rv[0]; }
        __syncthreads();
    }

    if (tid < 4) {
        newlp[bi * NB + tid] = winv[tid];
        beams[bi * NB + tid] = win[tid];
    }
}

// ---------------------------------------------------------------- state update
__global__ void update_kernel(const int* __restrict__ beams, const float* __restrict__ newlp,
                              float* __restrict__ lp, int* __restrict__ fin,
                              int* __restrict__ tokens, int* __restrict__ pidx,
                              int* __restrict__ bo, int t)
{
    int b = threadIdx.x;
    int flat = beams[b];
    int q = flat / VV;
    int p = q + ((b >> 2) << 2);
    int tok = flat - q * VV;
    int oldfin = fin[p];
    int col[TSTEPS + 1];
    #pragma unroll
    for (int r = 0; r <= TSTEPS; r++) col[r] = bo[r * BB + p];
    __syncthreads();
    #pragma unroll
    for (int r = 0; r <= TSTEPS; r++) bo[r * BB + b] = col[r];
    bo[(t + 1) * BB + b] = tok;
    fin[b]    = oldfin | (tok == EOSTOK);
    lp[b]     = newlp[b];
    tokens[b] = tok;
    pidx[b]   = p;
}

// ---------------------------------------------------------------- final beam_out -> float
__global__ void final_kernel(const int* __restrict__ bo, float* __restrict__ out)
{
    int i = blockIdx.x * blockDim.x + threadIdx.x;
    if (i < (TSTEPS + 1) * BB) out[i] = (float)bo[i];
}

// ---------------------------------------------------------------- host
extern "C" void kernel_launch(void* const* d_in, const int* in_sizes, int n_in,
                              void* d_out, int out_size, void* d_ws, size_t ws_size,
                              hipStream_t stream)
{
    const int*   inputs = (const int*)d_in[0];
    const float* h0   = (const float*)d_in[1];
    const float* c0   = (const float*)d_in[2];
    const float* emb  = (const float*)d_in[3];
    const float* Wih0 = (const float*)d_in[4];
    const float* Whh0 = (const float*)d_in[5];
    const float* b0   = (const float*)d_in[6];
    const float* Wih1 = (const float*)d_in[7];
    const float* Whh1 = (const float*)d_in[8];
    const float* b1   = (const float*)d_in[9];
    const float* Wp   = (const float*)d_in[10];
    const float* bp   = (const float*)d_in[11];
    float* out = (float*)d_out;

    char* w = (char*)d_ws;
    size_t off = 0;
    auto alloc = [&](size_t bytes) { void* p = w + off; off += (bytes + 255) & ~255ULL; return p; };
    double* h0c = (double*)alloc(BB * DD * 8);
    double* c0c = (double*)alloc(BB * DD * 8);
    double* h1c = (double*)alloc(BB * DD * 8);
    double* c1c = (double*)alloc(BB * DD * 8);
    double* xg  = (double*)alloc(BB * DD * 8);
    double* hg0 = (double*)alloc(BB * DD * 8);
    double* cg0 = (double*)alloc(BB * DD * 8);
    double* hg1 = (double*)alloc(BB * DD * 8);
    double* cg1 = (double*)alloc(BB * DD * 8);
    double* outd  = (double*)alloc((size_t)BB * VV * 8);
    double* lse   = (double*)alloc(BB * 8);
    float* lp    = (float*)alloc(BB * 4);
    float* newlp = (float*)alloc(BB * 4);
    int* beams  = (int*)alloc(BB * 4);
    int* pidx   = (int*)alloc(BB * 4);
    int* tokens = (int*)alloc(BB * 4);
    int* fin    = (int*)alloc(BB * 4);
    int* bo     = (int*)alloc((TSTEPS + 1) * BB * 4);

    init_kernel<<<128, 256, 0, stream>>>(inputs, h0, c0, h0c, c0c, h1c, c1c,
                                         tokens, pidx, fin, lp, bo);

    for (int t = 0; t < TSTEPS; t++) {
        gather_kernel<<<BB, 256, 0, stream>>>(emb, tokens, pidx,
                                              h0c, c0c, h1c, c1c,
                                              xg, hg0, cg0, hg1, cg1);
        lstm_kernel<<<BB, 512, 0, stream>>>(xg, hg0, cg0, Wih0, Whh0, b0, h0c, c0c);
        lstm_kernel<<<BB, 512, 0, stream>>>(h0c, hg1, cg1, Wih1, Whh1, b1, h1c, c1c);

        float* outf = out + (size_t)t * BB * VV;
        proj_kernel<<<VV / 128, 256, 0, stream>>>(h1c, Wp, bp, outf, outd);
        lse_kernel<<<BB, 256, 0, stream>>>(outd, lse);
        topk_kernel<<<BS, 256, 0, stream>>>(outd, lse, lp, fin, newlp, beams, t == 0 ? 1 : 0);
        update_kernel<<<1, 64, 0, stream>>>(beams, newlp, lp, fin, tokens, pidx, bo, t);
    }
    final_kernel<<<5, 256, 0, stream>>>(bo, out + (size_t)TSTEPS * BB * VV);
}

// Round 7
// 6574.695 us; speedup vs baseline: 4.8672x; 4.8672x over previous
//
#include <hip/hip_runtime.h>
#include <math.h>

#define BS     16
#define NB     4
#define BB     64      // BS*NB
#define DD     512
#define VV     32000
#define TSTEPS 16
#define EOSTOK 2
#define NEGF   (-1e32f)

__device__ __forceinline__ bool better(float av, int ai, float bv, int bi_) {
    return (av > bv) || (av == bv && ai < bi_);
}

// ---------------------------------------------------------------- init (fp32 states)
__global__ void init_kernel(const int* __restrict__ inputs,
                            const float* __restrict__ h0, const float* __restrict__ c0,
                            float* __restrict__ h0s, float* __restrict__ c0s,
                            float* __restrict__ h1s, float* __restrict__ c1s,
                            int* __restrict__ tokens, int* __restrict__ pidx,
                            int* __restrict__ fin, float* __restrict__ lp,
                            int* __restrict__ bo)
{
    int tid = blockIdx.x * blockDim.x + threadIdx.x;
    int total = BB * DD;
    for (int i = tid; i < total; i += gridDim.x * blockDim.x) {
        int b = i / DD;
        int d = i % DD;
        int src0 = 0 * BS * DD + (b >> 2) * DD + d;
        int src1 = 1 * BS * DD + (b >> 2) * DD + d;
        h0s[i] = h0[src0];
        c0s[i] = c0[src0];
        h1s[i] = h0[src1];
        c1s[i] = c0[src1];
    }
    if (tid < BB) {
        tokens[tid] = inputs[tid >> 2];
        pidx[tid]   = tid;
        fin[tid]    = 0;
        lp[tid]     = 0.0f;
        bo[0 * BB + tid] = inputs[tid >> 2];
        for (int r = 1; r <= TSTEPS; r++) bo[r * BB + tid] = 0;
    }
}

// ---------------------------------------------------------------- LSTM (j-tiled, fp64 acc, fp32 state)
// grid 128 blocks (4 j each), 256 threads: thread=(b 0..63, jj 0..3), j = blk*4+jj.
// x gathered via xrow (or identity if null); h/c gathered via prow.
__global__ __launch_bounds__(256) void lstm_kernel(
    const float* __restrict__ xbase, const int* __restrict__ xrow,
    const float* __restrict__ hsrc,  const float* __restrict__ csrc,
    const int* __restrict__ prow,
    float* __restrict__ hdst, float* __restrict__ cdst,
    const float* __restrict__ Wih, const float* __restrict__ Whh,
    const float* __restrict__ bias)
{
    __shared__ float U[64][133];   // stride 133: (133*b+k)%32 spreads banks
    int tid = threadIdx.x;
    int b  = tid & 63;
    int jj = tid >> 6;             // 0..3
    int j  = blockIdx.x * 4 + jj;

    double a0 = 0.0, a1 = 0.0, a2 = 0.0, a3 = 0.0;

    for (int ch = 0; ch < 8; ch++) {          // 8 chunks of 128 over K=1024 (x:0..3, h:4..7)
        int k0 = ch * 128;
        __syncthreads();
        #pragma unroll
        for (int i = 0; i < 32; i++) {        // 256 thr x 32 = 64x128 cooperative load
            int e  = tid + i * 256;
            int bb = e >> 7;
            int kk = e & 127;
            float v;
            if (k0 < 512) {
                int xr = xrow ? xrow[bb] : bb;
                v = xbase[(size_t)xr * DD + k0 + kk];
            } else {
                v = hsrc[prow[bb] * DD + (k0 - 512) + kk];
            }
            U[bb][kk] = v;
        }
        __syncthreads();
        const float* Wc = (k0 < 512) ? Wih : Whh;
        int kof = (k0 < 512) ? k0 : (k0 - 512);
        const float* w0 = Wc + (size_t)(0 * DD + j) * DD + kof;
        const float* w1 = Wc + (size_t)(1 * DD + j) * DD + kof;
        const float* w2 = Wc + (size_t)(2 * DD + j) * DD + kof;
        const float* w3 = Wc + (size_t)(3 * DD + j) * DD + kof;
        #pragma unroll 4
        for (int kk = 0; kk < 128; kk++) {
            double u = (double)U[b][kk];
            a0 = fma(u, (double)w0[kk], a0);
            a1 = fma(u, (double)w1[kk], a1);
            a2 = fma(u, (double)w2[kk], a2);
            a3 = fma(u, (double)w3[kk], a3);
        }
    }

    double zi = a0 + (double)bias[0 * DD + j];
    double zf = a1 + (double)bias[1 * DD + j];
    double zg = a2 + (double)bias[2 * DD + j];
    double zo = a3 + (double)bias[3 * DD + j];
    double si = 1.0 / (1.0 + exp(-zi));
    double sf = 1.0 / (1.0 + exp(-zf));
    double so = 1.0 / (1.0 + exp(-zo));
    double cold = (double)csrc[prow[b] * DD + j];
    double cn = sf * cold + si * tanh(zg);
    double hn = so * tanh(cn);
    hdst[b * DD + j] = (float)hn;   // fp32 boundary (ref semantics)
    cdst[b * DD + j] = (float)cn;
}

// ---------------------------------------------------------------- projection GEMM (fp64 acc, fp32 logits)
__global__ __launch_bounds__(256) void proj_kernel(
    const float* __restrict__ h1, const float* __restrict__ Wp,
    const float* __restrict__ bp, float* __restrict__ outf)
{
    __shared__ float sh[32][68];    // [k][b], float4-aligned rows
    __shared__ float sw[32][136];   // [k][v]
    int tid = threadIdx.x;
    int v0 = blockIdx.x * 128;
    int tb = (tid >> 4) * 4;        // 0..60
    int tv = (tid & 15) * 8;        // 0..120

    double acc[4][8];
    #pragma unroll
    for (int a = 0; a < 4; a++)
        #pragma unroll
        for (int q = 0; q < 8; q++) acc[a][q] = 0.0;

    for (int ch = 0; ch < 16; ch++) {
        int k0 = ch * 32;
        __syncthreads();
        #pragma unroll
        for (int i = 0; i < 8; i++) {           // sh: 32k x 64b
            int e = tid + i * 256;
            int k = e >> 6;
            int b = e & 63;
            sh[k][b] = h1[b * DD + k0 + k];
        }
        #pragma unroll
        for (int i = 0; i < 16; i++) {          // sw: 32k x 128v
            int e = tid + i * 256;
            int v = e & 127;
            int k = e >> 7;
            sw[k][v] = Wp[(size_t)(k0 + k) * VV + v0 + v];
        }
        __syncthreads();
        #pragma unroll 4
        for (int k = 0; k < 32; k++) {
            float4 hv = *(const float4*)&sh[k][tb];
            float4 wa = *(const float4*)&sw[k][tv];
            float4 wb = *(const float4*)&sw[k][tv + 4];
            double hvv[4] = {(double)hv.x, (double)hv.y, (double)hv.z, (double)hv.w};
            double wvv[8] = {(double)wa.x, (double)wa.y, (double)wa.z, (double)wa.w,
                             (double)wb.x, (double)wb.y, (double)wb.z, (double)wb.w};
            #pragma unroll
            for (int q = 0; q < 8; q++) {
                acc[0][q] = fma(hvv[0], wvv[q], acc[0][q]);
                acc[1][q] = fma(hvv[1], wvv[q], acc[1][q]);
                acc[2][q] = fma(hvv[2], wvv[q], acc[2][q]);
                acc[3][q] = fma(hvv[3], wvv[q], acc[3][q]);
            }
        }
    }

    #pragma unroll
    for (int a = 0; a < 4; a++) {
        int brow = tb + a;
        #pragma unroll
        for (int q = 0; q < 8; q++) {
            int v = v0 + tv + q;
            outf[(size_t)brow * VV + v] = (float)(acc[a][q] + (double)bp[v]);  // fp32 boundary
        }
    }
}

// ---------------------------------------------------------------- per-row LSE + row top-4
// 64 blocks (one per row) x 1024 threads. Scores on fp32 grid, (val, lower-idx) order.
__global__ __launch_bounds__(1024) void row_kernel(
    const float* __restrict__ outf, const float* __restrict__ lp,
    const int* __restrict__ fin,
    float* __restrict__ rcv, int* __restrict__ rci, int step0)
{
    int row = blockIdx.x;
    int j   = row & 3;
    int tid = threadIdx.x;
    int base_idx = j * VV;

    float lp_r = step0 ? 0.0f : lp[row];
    int   f    = step0 ? 0    : fin[row];

    if (step0 && j != 0) {          // step0: only beam 0's row participates
        if (tid < 4) { rcv[row * 4 + tid] = NEGF; rci[row * 4 + tid] = base_idx + tid; }
        return;
    }
    if (f) {                         // finished row: PAD carries lp, rest NEG
        if (tid < 4) {
            rcv[row * 4 + tid] = (tid == 0) ? lp_r : NEGF;
            rci[row * 4 + tid] = base_idx + tid;
        }
        return;
    }

    const float* x = outf + (size_t)row * VV;
    __shared__ double red[1024];

    double m = -1e300;
    for (int i = tid; i < VV; i += 1024) m = fmax(m, (double)x[i]);
    red[tid] = m; __syncthreads();
    for (int s = 512; s > 0; s >>= 1) {
        if (tid < s) red[tid] = fmax(red[tid], red[tid + s]);
        __syncthreads();
    }
    m = red[0];
    __syncthreads();

    double sum = 0.0;
    for (int i = tid; i < VV; i += 1024) sum += exp((double)x[i] - m);
    red[tid] = sum; __syncthreads();
    for (int s = 512; s > 0; s >>= 1) {
        if (tid < s) red[tid] += red[tid + s];
        __syncthreads();
    }
    double lse = m + log(red[0]);
    __syncthreads();

    // per-thread sorted top-4
    float bv[4]; int bx[4];
    #pragma unroll
    for (int q = 0; q < 4; q++) { bv[q] = -3.4e38f; bx[q] = 0x7fffffff; }
    for (int i = tid; i < VV; i += 1024) {
        float lgp32 = (float)((double)x[i] - lse);        // fp32 log-softmax value
        float val   = (float)((double)lp_r + (double)lgp32); // exact fp32 add
        int idx = base_idx + i;
        if (better(val, idx, bv[3], bx[3])) {
            bv[3] = val; bx[3] = idx;
            #pragma unroll
            for (int s = 3; s > 0; s--) {
                if (better(bv[s], bx[s], bv[s - 1], bx[s - 1])) {
                    float tv2 = bv[s]; bv[s] = bv[s - 1]; bv[s - 1] = tv2;
                    int ti2 = bx[s]; bx[s] = bx[s - 1]; bx[s - 1] = ti2;
                }
            }
        }
    }

    __shared__ float sv[1024][4];
    __shared__ int   si_[1024][4];
    #pragma unroll
    for (int q = 0; q < 4; q++) { sv[tid][q] = bv[q]; si_[tid][q] = bx[q]; }
    __syncthreads();
    for (int s = 512; s > 0; s >>= 1) {
        if (tid < s) {
            float av[4], ov[4], mv[4]; int ai[4], oi[4], mi[4];
            #pragma unroll
            for (int q = 0; q < 4; q++) {
                av[q] = sv[tid][q];     ai[q] = si_[tid][q];
                ov[q] = sv[tid + s][q]; oi[q] = si_[tid + s][q];
            }
            int pa = 0, pb = 0;
            #pragma unroll
            for (int q = 0; q < 4; q++) {
                bool takeA = (pb >= 4) || (pa < 4 && better(av[pa], ai[pa], ov[pb], oi[pb]));
                if (takeA) { mv[q] = av[pa]; mi[q] = ai[pa]; pa++; }
                else       { mv[q] = ov[pb]; mi[q] = oi[pb]; pb++; }
            }
            #pragma unroll
            for (int q = 0; q < 4; q++) { sv[tid][q] = mv[q]; si_[tid][q] = mi[q]; }
        }
        __syncthreads();
    }
    if (tid < 4) {
        rcv[row * 4 + tid] = sv[0][tid];
        rci[row * 4 + tid] = si_[0][tid];
    }
}

// ---------------------------------------------------------------- merge 16 candidates/batch + state update
__global__ void merge_update_kernel(
    const float* __restrict__ rcv, const int* __restrict__ rci,
    float* __restrict__ lp, int* __restrict__ fin,
    int* __restrict__ tokens, int* __restrict__ pidx,
    int* __restrict__ bo, int t)
{
    int b = threadIdx.x;           // 64
    int bi = b >> 2, r = b & 3;

    float cv[16]; int ci[16];
    #pragma unroll
    for (int c = 0; c < 16; c++) { cv[c] = rcv[bi * 16 + c]; ci[c] = rci[bi * 16 + c]; }

    int sel = 0;
    #pragma unroll
    for (int c = 0; c < 16; c++) {
        int rank = 0;
        #pragma unroll
        for (int d = 0; d < 16; d++)
            if (d != c && better(cv[d], ci[d], cv[c], ci[c])) rank++;
        if (rank == r) sel = c;
    }

    float v = cv[sel];
    int flat = ci[sel];
    int q = flat / VV;
    int p = q + bi * 4;
    int tok = flat - q * VV;
    int oldfin = fin[p];
    int col[TSTEPS + 1];
    #pragma unroll
    for (int rr = 0; rr <= TSTEPS; rr++) col[rr] = bo[rr * BB + p];
    __syncthreads();
    #pragma unroll
    for (int rr = 0; rr <= TSTEPS; rr++) bo[rr * BB + b] = col[rr];
    bo[(t + 1) * BB + b] = tok;
    fin[b]    = oldfin | (tok == EOSTOK);
    lp[b]     = v;
    tokens[b] = tok;
    pidx[b]   = p;
}

// ---------------------------------------------------------------- final beam_out -> float
__global__ void final_kernel(const int* __restrict__ bo, float* __restrict__ out)
{
    int i = blockIdx.x * blockDim.x + threadIdx.x;
    if (i < (TSTEPS + 1) * BB) out[i] = (float)bo[i];
}

// ---------------------------------------------------------------- host
extern "C" void kernel_launch(void* const* d_in, const int* in_sizes, int n_in,
                              void* d_out, int out_size, void* d_ws, size_t ws_size,
                              hipStream_t stream)
{
    const int*   inputs = (const int*)d_in[0];
    const float* h0   = (const float*)d_in[1];
    const float* c0   = (const float*)d_in[2];
    const float* emb  = (const float*)d_in[3];
    const float* Wih0 = (const float*)d_in[4];
    const float* Whh0 = (const float*)d_in[5];
    const float* b0   = (const float*)d_in[6];
    const float* Wih1 = (const float*)d_in[7];
    const float* Whh1 = (const float*)d_in[8];
    const float* b1   = (const float*)d_in[9];
    const float* Wp   = (const float*)d_in[10];
    const float* bp   = (const float*)d_in[11];
    float* out = (float*)d_out;

    char* w = (char*)d_ws;
    size_t off = 0;
    auto alloc = [&](size_t bytes) { void* p = w + off; off += (bytes + 255) & ~255ULL; return p; };
    float* h0s[2], *c0s[2], *h1s[2], *c1s[2];
    for (int s = 0; s < 2; s++) {
        h0s[s] = (float*)alloc(BB * DD * 4);
        c0s[s] = (float*)alloc(BB * DD * 4);
        h1s[s] = (float*)alloc(BB * DD * 4);
        c1s[s] = (float*)alloc(BB * DD * 4);
    }
    float* rcv   = (float*)alloc(BB * 4 * 4);
    int*   rci   = (int*)alloc(BB * 4 * 4);
    float* lp    = (float*)alloc(BB * 4);
    int* pidx    = (int*)alloc(BB * 4);
    int* tokens  = (int*)alloc(BB * 4);
    int* fin     = (int*)alloc(BB * 4);
    int* bo      = (int*)alloc((TSTEPS + 1) * BB * 4);

    init_kernel<<<128, 256, 0, stream>>>(inputs, h0, c0,
                                         h0s[0], c0s[0], h1s[0], c1s[0],
                                         tokens, pidx, fin, lp, bo);

    for (int t = 0; t < TSTEPS; t++) {
        int s = t & 1, d2 = s ^ 1;
        // layer 0: x = emb[tokens], h/c via pidx
        lstm_kernel<<<128, 256, 0, stream>>>(emb, tokens, h0s[s], c0s[s], pidx,
                                             h0s[d2], c0s[d2], Wih0, Whh0, b0);
        // layer 1: x = new h0 (identity), h/c via pidx
        lstm_kernel<<<128, 256, 0, stream>>>(h0s[d2], nullptr, h1s[s], c1s[s], pidx,
                                             h1s[d2], c1s[d2], Wih1, Whh1, b1);

        float* outf = out + (size_t)t * BB * VV;
        proj_kernel<<<VV / 128, 256, 0, stream>>>(h1s[d2], Wp, bp, outf);
        row_kernel<<<BB, 1024, 0, stream>>>(outf, lp, fin, rcv, rci, t == 0 ? 1 : 0);
        merge_update_kernel<<<1, 64, 0, stream>>>(rcv, rci, lp, fin, tokens, pidx, bo, t);
    }
    final_kernel<<<5, 256, 0, stream>>>(bo, out + (size_t)TSTEPS * BB * VV);
}

// Round 8
// 4504.242 us; speedup vs baseline: 7.1045x; 1.4597x over previous
//
#include <hip/hip_runtime.h>
#include <math.h>

#define BS     16
#define NB     4
#define BB     64      // BS*NB
#define DD     512
#define VV     32000
#define TSTEPS 16
#define EOSTOK 2
#define NEGF   (-1e32f)
#define VT     64
#define NVT    (VV / VT)   // 500

__device__ __forceinline__ bool better(float av, int ai, float bv, int bi_) {
    return (av > bv) || (av == bv && ai < bi_);
}

// ---------------------------------------------------------------- init (fp32 states)
__global__ void init_kernel(const int* __restrict__ inputs,
                            const float* __restrict__ h0, const float* __restrict__ c0,
                            float* __restrict__ h0s, float* __restrict__ c0s,
                            float* __restrict__ h1s, float* __restrict__ c1s,
                            int* __restrict__ tokens, int* __restrict__ pidx,
                            int* __restrict__ fin, float* __restrict__ lp,
                            int* __restrict__ bo)
{
    int tid = blockIdx.x * blockDim.x + threadIdx.x;
    int total = BB * DD;
    for (int i = tid; i < total; i += gridDim.x * blockDim.x) {
        int b = i / DD;
        int d = i % DD;
        int src0 = 0 * BS * DD + (b >> 2) * DD + d;
        int src1 = 1 * BS * DD + (b >> 2) * DD + d;
        h0s[i] = h0[src0];
        c0s[i] = c0[src0];
        h1s[i] = h0[src1];
        c1s[i] = c0[src1];
    }
    if (tid < BB) {
        tokens[tid] = inputs[tid >> 2];
        pidx[tid]   = tid;
        fin[tid]    = 0;
        lp[tid]     = 0.0f;
        bo[0 * BB + tid] = inputs[tid >> 2];
        for (int r = 1; r <= TSTEPS; r++) bo[r * BB + tid] = 0;
    }
}

// ---------------------------------------------------------------- LSTM: one block per output unit j
// 512 blocks x 256 threads; thread = (b 0..63, gate 0..3). Wave = one gate -> weight
// row is wave-uniform (scalar loads). fp64 acc, fp32 h/c out (ref boundary).
__global__ __launch_bounds__(256) void lstm_kernel(
    const float* __restrict__ xbase, const int* __restrict__ xrow,
    const float* __restrict__ hsrc,  const float* __restrict__ csrc,
    const int* __restrict__ prow,
    float* __restrict__ hdst, float* __restrict__ cdst,
    const float* __restrict__ Wih, const float* __restrict__ Whh,
    const float* __restrict__ bias)
{
    __shared__ float U[64][129];   // [b][k] pad 129 -> banks (b+k)%32, 2-way max
    __shared__ double Z[4][64];
    __shared__ int rows_s[64], prows_s[64];
    int tid = threadIdx.x;
    int j = blockIdx.x;
    int b = tid & 63;
    int g = tid >> 6;

    if (tid < 64) {
        rows_s[tid]  = xrow ? xrow[tid] : tid;
        prows_s[tid] = prow[tid];
    }
    __syncthreads();

    double acc = 0.0;
    for (int ch = 0; ch < 8; ch++) {
        int k0 = ch * 128;
        __syncthreads();
        #pragma unroll
        for (int i = 0; i < 32; i++) {          // 64x128 cooperative stage
            int e = tid + i * 256;
            int kk = e & 127, bb = e >> 7;
            float v;
            if (k0 < 512) v = xbase[(size_t)rows_s[bb] * DD + k0 + kk];
            else          v = hsrc[(size_t)prows_s[bb] * DD + (k0 - 512) + kk];
            U[bb][kk] = v;
        }
        __syncthreads();
        const float* W = (k0 < 512) ? (Wih + (size_t)(g * DD + j) * DD + k0)
                                    : (Whh + (size_t)(g * DD + j) * DD + (k0 - 512));
        #pragma unroll 8
        for (int kk = 0; kk < 128; kk++)
            acc = fma((double)U[b][kk], (double)W[kk], acc);
    }
    Z[g][b] = acc;
    __syncthreads();

    if (tid < 64) {
        double zi = Z[0][b] + (double)bias[0 * DD + j];
        double zf = Z[1][b] + (double)bias[1 * DD + j];
        double zg = Z[2][b] + (double)bias[2 * DD + j];
        double zo = Z[3][b] + (double)bias[3 * DD + j];
        double si = 1.0 / (1.0 + exp(-zi));
        double sf = 1.0 / (1.0 + exp(-zf));
        double so = 1.0 / (1.0 + exp(-zo));
        double cold = (double)csrc[(size_t)prows_s[b] * DD + j];
        double cn = sf * cold + si * tanh(zg);
        double hn = so * tanh(cn);
        hdst[b * DD + j] = (float)hn;   // fp32 boundary
        cdst[b * DD + j] = (float)cn;
    }
}

// ---------------------------------------------------------------- projection GEMM, K-split x2
// grid = NVT*2 blocks (vtile, khalf), 256 threads, thread tile 4b x 4v, fp64 partials.
__global__ __launch_bounds__(256) void proj_kernel(
    const float* __restrict__ h1, const float* __restrict__ Wp,
    double* __restrict__ pp)
{
    __shared__ float sh[64][68];    // [b][k-chunk]
    __shared__ float sw[64][68];    // [k-chunk][v]
    int vtile = blockIdx.x % NVT;
    int kh    = blockIdx.x / NVT;   // 0 or 1
    int kbase = kh * 256;
    int vbase = vtile * VT;
    int tid = threadIdx.x;
    int b0 = (tid >> 4) * 4;        // 0..60
    int v0 = (tid & 15) * 4;        // 0..60

    double acc[4][4];
    #pragma unroll
    for (int i = 0; i < 4; i++)
        #pragma unroll
        for (int q = 0; q < 4; q++) acc[i][q] = 0.0;

    for (int ch = 0; ch < 4; ch++) {
        int k0 = kbase + ch * 64;
        __syncthreads();
        #pragma unroll
        for (int i = 0; i < 16; i++) {          // sh: [b][k], coalesced k per lane
            int e = tid + i * 256;
            int bb = e >> 6, kk = e & 63;
            sh[bb][kk] = h1[bb * DD + k0 + kk];
        }
        #pragma unroll
        for (int i = 0; i < 16; i++) {          // sw: [k][v], coalesced v per lane
            int e = tid + i * 256;
            int kk = e >> 6, vv = e & 63;
            sw[kk][vv] = Wp[(size_t)(k0 + kk) * VV + vbase + vv];
        }
        __syncthreads();
        #pragma unroll
        for (int k4 = 0; k4 < 16; k4++) {
            int k = k4 * 4;
            float4 h4[4], w4[4];
            #pragma unroll
            for (int i = 0; i < 4; i++) h4[i] = *(const float4*)&sh[b0 + i][k];
            #pragma unroll
            for (int kk = 0; kk < 4; kk++) w4[kk] = *(const float4*)&sw[k + kk][v0];
            #pragma unroll
            for (int i = 0; i < 4; i++) {
                const float hh[4] = {h4[i].x, h4[i].y, h4[i].z, h4[i].w};
                #pragma unroll
                for (int kk = 0; kk < 4; kk++) {
                    double hd = (double)hh[kk];
                    const float ww[4] = {w4[kk].x, w4[kk].y, w4[kk].z, w4[kk].w};
                    #pragma unroll
                    for (int q = 0; q < 4; q++)
                        acc[i][q] = fma(hd, (double)ww[q], acc[i][q]);
                }
            }
        }
    }

    double* base = pp + (size_t)kh * BB * VV;
    #pragma unroll
    for (int i = 0; i < 4; i++)
        #pragma unroll
        for (int q = 0; q < 4; q++)
            base[(size_t)(b0 + i) * VV + vbase + v0 + q] = acc[i][q];
}

// ---------------------------------------------------------------- partial reduce + bias -> fp32 logits
__global__ __launch_bounds__(256) void reduce_kernel(
    const double* __restrict__ pp, const float* __restrict__ bp,
    float* __restrict__ outf)
{
    int i = blockIdx.x * 256 + threadIdx.x;
    if (i < BB * VV) {
        int v = i % VV;
        double z = (pp[i] + pp[(size_t)BB * VV + i]) + (double)bp[v];
        outf[i] = (float)z;   // fp32 boundary
    }
}

// ---------------------------------------------------------------- per-row LSE + row top-4
__global__ __launch_bounds__(1024) void row_kernel(
    const float* __restrict__ outf, const float* __restrict__ lp,
    const int* __restrict__ fin,
    float* __restrict__ rcv, int* __restrict__ rci, int step0)
{
    int row = blockIdx.x;
    int j   = row & 3;
    int tid = threadIdx.x;
    int base_idx = j * VV;

    float lp_r = step0 ? 0.0f : lp[row];
    int   f    = step0 ? 0    : fin[row];

    if (step0 && j != 0) {
        if (tid < 4) { rcv[row * 4 + tid] = NEGF; rci[row * 4 + tid] = base_idx + tid; }
        return;
    }
    if (f) {
        if (tid < 4) {
            rcv[row * 4 + tid] = (tid == 0) ? lp_r : NEGF;
            rci[row * 4 + tid] = base_idx + tid;
        }
        return;
    }

    const float* x = outf + (size_t)row * VV;
    __shared__ double red[1024];

    double m = -1e300;
    for (int i = tid; i < VV; i += 1024) m = fmax(m, (double)x[i]);
    red[tid] = m; __syncthreads();
    for (int s = 512; s > 0; s >>= 1) {
        if (tid < s) red[tid] = fmax(red[tid], red[tid + s]);
        __syncthreads();
    }
    m = red[0];
    __syncthreads();

    double sum = 0.0;
    for (int i = tid; i < VV; i += 1024) sum += exp((double)x[i] - m);
    red[tid] = sum; __syncthreads();
    for (int s = 512; s > 0; s >>= 1) {
        if (tid < s) red[tid] += red[tid + s];
        __syncthreads();
    }
    double lse = m + log(red[0]);
    __syncthreads();

    float bv[4]; int bx[4];
    #pragma unroll
    for (int q = 0; q < 4; q++) { bv[q] = -3.4e38f; bx[q] = 0x7fffffff; }
    for (int i = tid; i < VV; i += 1024) {
        float lgp32 = (float)((double)x[i] - lse);
        float val   = (float)((double)lp_r + (double)lgp32);
        int idx = base_idx + i;
        if (better(val, idx, bv[3], bx[3])) {
            bv[3] = val; bx[3] = idx;
            #pragma unroll
            for (int s = 3; s > 0; s--) {
                if (better(bv[s], bx[s], bv[s - 1], bx[s - 1])) {
                    float tv2 = bv[s]; bv[s] = bv[s - 1]; bv[s - 1] = tv2;
                    int ti2 = bx[s]; bx[s] = bx[s - 1]; bx[s - 1] = ti2;
                }
            }
        }
    }

    __shared__ float sv[1024][4];
    __shared__ int   si_[1024][4];
    #pragma unroll
    for (int q = 0; q < 4; q++) { sv[tid][q] = bv[q]; si_[tid][q] = bx[q]; }
    __syncthreads();
    for (int s = 512; s > 0; s >>= 1) {
        if (tid < s) {
            float av[4], ov[4], mv[4]; int ai[4], oi[4], mi[4];
            #pragma unroll
            for (int q = 0; q < 4; q++) {
                av[q] = sv[tid][q];     ai[q] = si_[tid][q];
                ov[q] = sv[tid + s][q]; oi[q] = si_[tid + s][q];
            }
            int pa = 0, pb = 0;
            #pragma unroll
            for (int q = 0; q < 4; q++) {
                bool takeA = (pb >= 4) || (pa < 4 && better(av[pa], ai[pa], ov[pb], oi[pb]));
                if (takeA) { mv[q] = av[pa]; mi[q] = ai[pa]; pa++; }
                else       { mv[q] = ov[pb]; mi[q] = oi[pb]; pb++; }
            }
            #pragma unroll
            for (int q = 0; q < 4; q++) { sv[tid][q] = mv[q]; si_[tid][q] = mi[q]; }
        }
        __syncthreads();
    }
    if (tid < 4) {
        rcv[row * 4 + tid] = sv[0][tid];
        rci[row * 4 + tid] = si_[0][tid];
    }
}

// ---------------------------------------------------------------- merge 16 candidates/batch + state update
__global__ void merge_update_kernel(
    const float* __restrict__ rcv, const int* __restrict__ rci,
    float* __restrict__ lp, int* __restrict__ fin,
    int* __restrict__ tokens, int* __restrict__ pidx,
    int* __restrict__ bo, int t)
{
    int b = threadIdx.x;           // 64
    int bi = b >> 2, r = b & 3;

    float cv[16]; int ci[16];
    #pragma unroll
    for (int c = 0; c < 16; c++) { cv[c] = rcv[bi * 16 + c]; ci[c] = rci[bi * 16 + c]; }

    int sel = 0;
    #pragma unroll
    for (int c = 0; c < 16; c++) {
        int rank = 0;
        #pragma unroll
        for (int d = 0; d < 16; d++)
            if (d != c && better(cv[d], ci[d], cv[c], ci[c])) rank++;
        if (rank == r) sel = c;
    }

    float v = cv[sel];
    int flat = ci[sel];
    int q = flat / VV;
    int p = q + bi * 4;
    int tok = flat - q * VV;
    int oldfin = fin[p];
    int col[TSTEPS + 1];
    #pragma unroll
    for (int rr = 0; rr <= TSTEPS; rr++) col[rr] = bo[rr * BB + p];
    __syncthreads();
    #pragma unroll
    for (int rr = 0; rr <= TSTEPS; rr++) bo[rr * BB + b] = col[rr];
    bo[(t + 1) * BB + b] = tok;
    fin[b]    = oldfin | (tok == EOSTOK);
    lp[b]     = v;
    tokens[b] = tok;
    pidx[b]   = p;
}

// ---------------------------------------------------------------- final beam_out -> float
__global__ void final_kernel(const int* __restrict__ bo, float* __restrict__ out)
{
    int i = blockIdx.x * blockDim.x + threadIdx.x;
    if (i < (TSTEPS + 1) * BB) out[i] = (float)bo[i];
}

// ---------------------------------------------------------------- host
extern "C" void kernel_launch(void* const* d_in, const int* in_sizes, int n_in,
                              void* d_out, int out_size, void* d_ws, size_t ws_size,
                              hipStream_t stream)
{
    const int*   inputs = (const int*)d_in[0];
    const float* h0   = (const float*)d_in[1];
    const float* c0   = (const float*)d_in[2];
    const float* emb  = (const float*)d_in[3];
    const float* Wih0 = (const float*)d_in[4];
    const float* Whh0 = (const float*)d_in[5];
    const float* b0   = (const float*)d_in[6];
    const float* Wih1 = (const float*)d_in[7];
    const float* Whh1 = (const float*)d_in[8];
    const float* b1   = (const float*)d_in[9];
    const float* Wp   = (const float*)d_in[10];
    const float* bp   = (const float*)d_in[11];
    float* out = (float*)d_out;

    char* w = (char*)d_ws;
    size_t off = 0;
    auto alloc = [&](size_t bytes) { void* p = w + off; off += (bytes + 255) & ~255ULL; return p; };
    double* pp = (double*)alloc((size_t)2 * BB * VV * 8);   // 32.8 MB fp64 K-split partials
    float* h0s[2], *c0s[2], *h1s[2], *c1s[2];
    for (int s = 0; s < 2; s++) {
        h0s[s] = (float*)alloc(BB * DD * 4);
        c0s[s] = (float*)alloc(BB * DD * 4);
        h1s[s] = (float*)alloc(BB * DD * 4);
        c1s[s] = (float*)alloc(BB * DD * 4);
    }
    float* rcv   = (float*)alloc(BB * 4 * 4);
    int*   rci   = (int*)alloc(BB * 4 * 4);
    float* lp    = (float*)alloc(BB * 4);
    int* pidx    = (int*)alloc(BB * 4);
    int* tokens  = (int*)alloc(BB * 4);
    int* fin     = (int*)alloc(BB * 4);
    int* bo      = (int*)alloc((TSTEPS + 1) * BB * 4);

    init_kernel<<<128, 256, 0, stream>>>(inputs, h0, c0,
                                         h0s[0], c0s[0], h1s[0], c1s[0],
                                         tokens, pidx, fin, lp, bo);

    for (int t = 0; t < TSTEPS; t++) {
        int s = t & 1, d2 = s ^ 1;
        lstm_kernel<<<512, 256, 0, stream>>>(emb, tokens, h0s[s], c0s[s], pidx,
                                             h0s[d2], c0s[d2], Wih0, Whh0, b0);
        lstm_kernel<<<512, 256, 0, stream>>>(h0s[d2], nullptr, h1s[s], c1s[s], pidx,
                                             h1s[d2], c1s[d2], Wih1, Whh1, b1);

        float* outf = out + (size_t)t * BB * VV;
        proj_kernel<<<NVT * 2, 256, 0, stream>>>(h1s[d2], Wp, pp);
        reduce_kernel<<<(BB * VV + 255) / 256, 256, 0, stream>>>(pp, bp, outf);
        row_kernel<<<BB, 1024, 0, stream>>>(outf, lp, fin, rcv, rci, t == 0 ? 1 : 0);
        merge_update_kernel<<<1, 64, 0, stream>>>(rcv, rci, lp, fin, tokens, pidx, bo, t);
    }
    final_kernel<<<5, 256, 0, stream>>>(bo, out + (size_t)TSTEPS * BB * VV);
}

// Round 9
// 4426.559 us; speedup vs baseline: 7.2292x; 1.0175x over previous
//
#include <hip/hip_runtime.h>
#include <math.h>

#define BS     16
#define NB     4
#define BB     64      // BS*NB
#define DD     512
#define VV     32000
#define TSTEPS 16
#define EOSTOK 2
#define NEGF   (-1e32f)
#define VT     64
#define NVT    (VV / VT)   // 500

__device__ __forceinline__ bool better(float av, int ai, float bv, int bi_) {
    return (av > bv) || (av == bv && ai < bi_);
}

// ---------------------------------------------------------------- init (fp32 states)
__global__ void init_kernel(const int* __restrict__ inputs,
                            const float* __restrict__ h0, const float* __restrict__ c0,
                            float* __restrict__ h0s, float* __restrict__ c0s,
                            float* __restrict__ h1s, float* __restrict__ c1s,
                            int* __restrict__ tokens, int* __restrict__ pidx,
                            int* __restrict__ fin, float* __restrict__ lp,
                            int* __restrict__ bo)
{
    int tid = blockIdx.x * blockDim.x + threadIdx.x;
    int total = BB * DD;
    for (int i = tid; i < total; i += gridDim.x * blockDim.x) {
        int b = i / DD;
        int d = i % DD;
        int src0 = 0 * BS * DD + (b >> 2) * DD + d;
        int src1 = 1 * BS * DD + (b >> 2) * DD + d;
        h0s[i] = h0[src0];
        c0s[i] = c0[src0];
        h1s[i] = h0[src1];
        c1s[i] = c0[src1];
    }
    if (tid < BB) {
        tokens[tid] = inputs[tid >> 2];
        pidx[tid]   = tid;
        fin[tid]    = 0;
        lp[tid]     = 0.0f;
        bo[0 * BB + tid] = inputs[tid >> 2];
        for (int r = 1; r <= TSTEPS; r++) bo[r * BB + tid] = 0;
    }
}

// ---------------------------------------------------------------- LSTM: one block per output unit j
// 512 blocks x 256 threads; thread = (b 0..63, gate 0..3). 4-way ILP fp64 accumulators.
__global__ __launch_bounds__(256) void lstm_kernel(
    const float* __restrict__ xbase, const int* __restrict__ xrow,
    const float* __restrict__ hsrc,  const float* __restrict__ csrc,
    const int* __restrict__ prow,
    float* __restrict__ hdst, float* __restrict__ cdst,
    const float* __restrict__ Wih, const float* __restrict__ Whh,
    const float* __restrict__ bias)
{
    __shared__ float U[64][129];   // [b][k]: bank (b+k)%32, 2-way max (free)
    __shared__ double Z[4][64];
    __shared__ int rows_s[64], prows_s[64];
    int tid = threadIdx.x;
    int j = blockIdx.x;
    int b = tid & 63;
    int g = tid >> 6;

    if (tid < 64) {
        rows_s[tid]  = xrow ? xrow[tid] : tid;
        prows_s[tid] = prow[tid];
    }
    __syncthreads();

    double a0 = 0.0, a1 = 0.0, a2 = 0.0, a3 = 0.0;   // ILP-4 chains
    for (int ch = 0; ch < 8; ch++) {
        int k0 = ch * 128;
        __syncthreads();
        #pragma unroll
        for (int i = 0; i < 32; i++) {          // 64x128 cooperative stage
            int e = tid + i * 256;
            int kk = e & 127, bb = e >> 7;
            float v;
            if (k0 < 512) v = xbase[(size_t)rows_s[bb] * DD + k0 + kk];
            else          v = hsrc[(size_t)prows_s[bb] * DD + (k0 - 512) + kk];
            U[bb][kk] = v;
        }
        __syncthreads();
        const float* W = (k0 < 512) ? (Wih + (size_t)(g * DD + j) * DD + k0)
                                    : (Whh + (size_t)(g * DD + j) * DD + (k0 - 512));
        #pragma unroll 8
        for (int kk = 0; kk < 128; kk += 4) {
            a0 = fma((double)U[b][kk + 0], (double)W[kk + 0], a0);
            a1 = fma((double)U[b][kk + 1], (double)W[kk + 1], a1);
            a2 = fma((double)U[b][kk + 2], (double)W[kk + 2], a2);
            a3 = fma((double)U[b][kk + 3], (double)W[kk + 3], a3);
        }
    }
    Z[g][b] = ((a0 + a1) + (a2 + a3));
    __syncthreads();

    if (tid < 64) {
        double zi = Z[0][b] + (double)bias[0 * DD + j];
        double zf = Z[1][b] + (double)bias[1 * DD + j];
        double zg = Z[2][b] + (double)bias[2 * DD + j];
        double zo = Z[3][b] + (double)bias[3 * DD + j];
        double si = 1.0 / (1.0 + exp(-zi));
        double sf = 1.0 / (1.0 + exp(-zf));
        double so = 1.0 / (1.0 + exp(-zo));
        double cold = (double)csrc[(size_t)prows_s[b] * DD + j];
        double cn = sf * cold + si * tanh(zg);
        double hn = so * tanh(cn);
        hdst[b * DD + j] = (float)hn;   // fp32 boundary
        cdst[b * DD + j] = (float)cn;
    }
}

// ---------------------------------------------------------------- projection GEMM, K-split x2
__global__ __launch_bounds__(256) void proj_kernel(
    const float* __restrict__ h1, const float* __restrict__ Wp,
    double* __restrict__ pp)
{
    __shared__ float sh[64][68];    // [b][k-chunk]
    __shared__ float sw[64][68];    // [k-chunk][v]
    int vtile = blockIdx.x % NVT;
    int kh    = blockIdx.x / NVT;   // 0 or 1
    int kbase = kh * 256;
    int vbase = vtile * VT;
    int tid = threadIdx.x;
    int b0 = (tid >> 4) * 4;
    int v0 = (tid & 15) * 4;

    double acc[4][4];
    #pragma unroll
    for (int i = 0; i < 4; i++)
        #pragma unroll
        for (int q = 0; q < 4; q++) acc[i][q] = 0.0;

    for (int ch = 0; ch < 4; ch++) {
        int k0 = kbase + ch * 64;
        __syncthreads();
        #pragma unroll
        for (int i = 0; i < 16; i++) {
            int e = tid + i * 256;
            int bb = e >> 6, kk = e & 63;
            sh[bb][kk] = h1[bb * DD + k0 + kk];
        }
        #pragma unroll
        for (int i = 0; i < 16; i++) {
            int e = tid + i * 256;
            int kk = e >> 6, vv = e & 63;
            sw[kk][vv] = Wp[(size_t)(k0 + kk) * VV + vbase + vv];
        }
        __syncthreads();
        #pragma unroll
        for (int k4 = 0; k4 < 16; k4++) {
            int k = k4 * 4;
            float4 h4[4], w4[4];
            #pragma unroll
            for (int i = 0; i < 4; i++) h4[i] = *(const float4*)&sh[b0 + i][k];
            #pragma unroll
            for (int kk = 0; kk < 4; kk++) w4[kk] = *(const float4*)&sw[k + kk][v0];
            #pragma unroll
            for (int i = 0; i < 4; i++) {
                const float hh[4] = {h4[i].x, h4[i].y, h4[i].z, h4[i].w};
                #pragma unroll
                for (int kk = 0; kk < 4; kk++) {
                    double hd = (double)hh[kk];
                    const float ww[4] = {w4[kk].x, w4[kk].y, w4[kk].z, w4[kk].w};
                    #pragma unroll
                    for (int q = 0; q < 4; q++)
                        acc[i][q] = fma(hd, (double)ww[q], acc[i][q]);
                }
            }
        }
    }

    double* base = pp + (size_t)kh * BB * VV;
    #pragma unroll
    for (int i = 0; i < 4; i++)
        #pragma unroll
        for (int q = 0; q < 4; q++)
            base[(size_t)(b0 + i) * VV + vbase + v0 + q] = acc[i][q];
}

// ---------------------------------------------------------------- fused reduce + LSE + row top-4
// 64 blocks x 1024 threads. Pass1: z=fp32((pp0+pp1)+bias), write logits, cache in regs.
#define NPT 32   // ceil(32000/1024)
__global__ __launch_bounds__(1024) void row_kernel(
    const double* __restrict__ pp, const float* __restrict__ bp,
    float* __restrict__ outf, const float* __restrict__ lp,
    const int* __restrict__ fin,
    float* __restrict__ rcv, int* __restrict__ rci, int step0)
{
    int row = blockIdx.x;
    int j   = row & 3;
    int tid = threadIdx.x;
    int base_idx = j * VV;

    const double* p0 = pp + (size_t)row * VV;
    const double* p1 = pp + (size_t)BB * VV + (size_t)row * VV;
    float* xo = outf + (size_t)row * VV;

    __shared__ double red[1024];

    // ---- pass 1: compute fp32 logits, write, cache, max
    float zreg[NPT];
    double m = -1e300;
    #pragma unroll
    for (int q = 0; q < NPT; q++) {
        int i = tid + q * 1024;
        float zf = 0.0f;
        if (i < VV) {
            double z = (p0[i] + p1[i]) + (double)bp[i];
            zf = (float)z;                 // fp32 boundary
            xo[i] = zf;
            m = fmax(m, (double)zf);
        }
        zreg[q] = zf;
    }

    float lp_r = step0 ? 0.0f : lp[row];
    int   f    = step0 ? 0    : fin[row];
    if (step0 && j != 0) {
        if (tid < 4) { rcv[row * 4 + tid] = NEGF; rci[row * 4 + tid] = base_idx + tid; }
        return;
    }
    if (f) {
        if (tid < 4) {
            rcv[row * 4 + tid] = (tid == 0) ? lp_r : NEGF;
            rci[row * 4 + tid] = base_idx + tid;
        }
        return;
    }

    red[tid] = m; __syncthreads();
    for (int s = 512; s > 0; s >>= 1) {
        if (tid < s) red[tid] = fmax(red[tid], red[tid + s]);
        __syncthreads();
    }
    m = red[0];
    __syncthreads();

    // ---- pass 2: sumexp from registers
    double sum = 0.0;
    #pragma unroll
    for (int q = 0; q < NPT; q++) {
        int i = tid + q * 1024;
        if (i < VV) sum += exp((double)zreg[q] - m);
    }
    red[tid] = sum; __syncthreads();
    for (int s = 512; s > 0; s >>= 1) {
        if (tid < s) red[tid] += red[tid + s];
        __syncthreads();
    }
    double lse = m + log(red[0]);
    __syncthreads();

    // ---- pass 3: per-thread top-4 from registers
    float bv[4]; int bx[4];
    #pragma unroll
    for (int q = 0; q < 4; q++) { bv[q] = -3.4e38f; bx[q] = 0x7fffffff; }
    #pragma unroll
    for (int q = 0; q < NPT; q++) {
        int i = tid + q * 1024;
        if (i < VV) {
            float lgp32 = (float)((double)zreg[q] - lse);
            float val   = (float)((double)lp_r + (double)lgp32);
            int idx = base_idx + i;
            if (better(val, idx, bv[3], bx[3])) {
                bv[3] = val; bx[3] = idx;
                #pragma unroll
                for (int s = 3; s > 0; s--) {
                    if (better(bv[s], bx[s], bv[s - 1], bx[s - 1])) {
                        float tv2 = bv[s]; bv[s] = bv[s - 1]; bv[s - 1] = tv2;
                        int ti2 = bx[s]; bx[s] = bx[s - 1]; bx[s - 1] = ti2;
                    }
                }
            }
        }
    }

    __shared__ float sv[1024][4];
    __shared__ int   si_[1024][4];
    #pragma unroll
    for (int q = 0; q < 4; q++) { sv[tid][q] = bv[q]; si_[tid][q] = bx[q]; }
    __syncthreads();
    for (int s = 512; s > 0; s >>= 1) {
        if (tid < s) {
            float av[4], ov[4], mv[4]; int ai[4], oi[4], mi[4];
            #pragma unroll
            for (int q = 0; q < 4; q++) {
                av[q] = sv[tid][q];     ai[q] = si_[tid][q];
                ov[q] = sv[tid + s][q]; oi[q] = si_[tid + s][q];
            }
            int pa = 0, pb = 0;
            #pragma unroll
            for (int q = 0; q < 4; q++) {
                bool takeA = (pb >= 4) || (pa < 4 && better(av[pa], ai[pa], ov[pb], oi[pb]));
                if (takeA) { mv[q] = av[pa]; mi[q] = ai[pa]; pa++; }
                else       { mv[q] = ov[pb]; mi[q] = oi[pb]; pb++; }
            }
            #pragma unroll
            for (int q = 0; q < 4; q++) { sv[tid][q] = mv[q]; si_[tid][q] = mi[q]; }
        }
        __syncthreads();
    }
    if (tid < 4) {
        rcv[row * 4 + tid] = sv[0][tid];
        rci[row * 4 + tid] = si_[0][tid];
    }
}

// ---------------------------------------------------------------- merge 16 candidates/batch + state update
__global__ void merge_update_kernel(
    const float* __restrict__ rcv, const int* __restrict__ rci,
    float* __restrict__ lp, int* __restrict__ fin,
    int* __restrict__ tokens, int* __restrict__ pidx,
    int* __restrict__ bo, int t)
{
    int b = threadIdx.x;           // 64
    int bi = b >> 2, r = b & 3;

    float cv[16]; int ci[16];
    #pragma unroll
    for (int c = 0; c < 16; c++) { cv[c] = rcv[bi * 16 + c]; ci[c] = rci[bi * 16 + c]; }

    int sel = 0;
    #pragma unroll
    for (int c = 0; c < 16; c++) {
        int rank = 0;
        #pragma unroll
        for (int d = 0; d < 16; d++)
            if (d != c && better(cv[d], ci[d], cv[c], ci[c])) rank++;
        if (rank == r) sel = c;
    }

    float v = cv[sel];
    int flat = ci[sel];
    int q = flat / VV;
    int p = q + bi * 4;
    int tok = flat - q * VV;
    int oldfin = fin[p];
    int col[TSTEPS + 1];
    #pragma unroll
    for (int rr = 0; rr <= TSTEPS; rr++) col[rr] = bo[rr * BB + p];
    __syncthreads();
    #pragma unroll
    for (int rr = 0; rr <= TSTEPS; rr++) bo[rr * BB + b] = col[rr];
    bo[(t + 1) * BB + b] = tok;
    fin[b]    = oldfin | (tok == EOSTOK);
    lp[b]     = v;
    tokens[b] = tok;
    pidx[b]   = p;
}

// ---------------------------------------------------------------- final beam_out -> float
__global__ void final_kernel(const int* __restrict__ bo, float* __restrict__ out)
{
    int i = blockIdx.x * blockDim.x + threadIdx.x;
    if (i < (TSTEPS + 1) * BB) out[i] = (float)bo[i];
}

// ---------------------------------------------------------------- host
extern "C" void kernel_launch(void* const* d_in, const int* in_sizes, int n_in,
                              void* d_out, int out_size, void* d_ws, size_t ws_size,
                              hipStream_t stream)
{
    const int*   inputs = (const int*)d_in[0];
    const float* h0   = (const float*)d_in[1];
    const float* c0   = (const float*)d_in[2];
    const float* emb  = (const float*)d_in[3];
    const float* Wih0 = (const float*)d_in[4];
    const float* Whh0 = (const float*)d_in[5];
    const float* b0   = (const float*)d_in[6];
    const float* Wih1 = (const float*)d_in[7];
    const float* Whh1 = (const float*)d_in[8];
    const float* b1   = (const float*)d_in[9];
    const float* Wp   = (const float*)d_in[10];
    const float* bp   = (const float*)d_in[11];
    float* out = (float*)d_out;

    char* w = (char*)d_ws;
    size_t off = 0;
    auto alloc = [&](size_t bytes) { void* p = w + off; off += (bytes + 255) & ~255ULL; return p; };
    double* pp = (double*)alloc((size_t)2 * BB * VV * 8);   // fp64 K-split partials
    float* h0s[2], *c0s[2], *h1s[2], *c1s[2];
    for (int s = 0; s < 2; s++) {
        h0s[s] = (float*)alloc(BB * DD * 4);
        c0s[s] = (float*)alloc(BB * DD * 4);
        h1s[s] = (float*)alloc(BB * DD * 4);
        c1s[s] = (float*)alloc(BB * DD * 4);
    }
    float* rcv   = (float*)alloc(BB * 4 * 4);
    int*   rci   = (int*)alloc(BB * 4 * 4);
    float* lp    = (float*)alloc(BB * 4);
    int* pidx    = (int*)alloc(BB * 4);
    int* tokens  = (int*)alloc(BB * 4);
    int* fin     = (int*)alloc(BB * 4);
    int* bo      = (int*)alloc((TSTEPS + 1) * BB * 4);

    init_kernel<<<128, 256, 0, stream>>>(inputs, h0, c0,
                                         h0s[0], c0s[0], h1s[0], c1s[0],
                                         tokens, pidx, fin, lp, bo);

    for (int t = 0; t < TSTEPS; t++) {
        int s = t & 1, d2 = s ^ 1;
        lstm_kernel<<<512, 256, 0, stream>>>(emb, tokens, h0s[s], c0s[s], pidx,
                                             h0s[d2], c0s[d2], Wih0, Whh0, b0);
        lstm_kernel<<<512, 256, 0, stream>>>(h0s[d2], nullptr, h1s[s], c1s[s], pidx,
                                             h1s[d2], c1s[d2], Wih1, Whh1, b1);

        float* outf = out + (size_t)t * BB * VV;
        proj_kernel<<<NVT * 2, 256, 0, stream>>>(h1s[d2], Wp, pp);
        row_kernel<<<BB, 1024, 0, stream>>>(pp, bp, outf, lp, fin, rcv, rci, t == 0 ? 1 : 0);
        merge_update_kernel<<<1, 64, 0, stream>>>(rcv, rci, lp, fin, tokens, pidx, bo, t);
    }
    final_kernel<<<5, 256, 0, stream>>>(bo, out + (size_t)TSTEPS * BB * VV);
}

// Round 10
// 4196.531 us; speedup vs baseline: 7.6254x; 1.0548x over previous
//
#include <hip/hip_runtime.h>
#include <math.h>

#define BS     16
#define NB     4
#define BB     64      // BS*NB
#define DD     512
#define VV     32000
#define TSTEPS 16
#define EOSTOK 2
#define NEGF   (-1e32f)
#define VT     64
#define NVT    (VV / VT)   // 500

__device__ __forceinline__ bool better(float av, int ai, float bv, int bi_) {
    return (av > bv) || (av == bv && ai < bi_);
}

// ---------------------------------------------------------------- init (fp32 states)
__global__ void init_kernel(const int* __restrict__ inputs,
                            const float* __restrict__ h0, const float* __restrict__ c0,
                            float* __restrict__ h0s, float* __restrict__ c0s,
                            float* __restrict__ h1s, float* __restrict__ c1s,
                            int* __restrict__ tokens, int* __restrict__ pidx,
                            int* __restrict__ fin, float* __restrict__ lp,
                            int* __restrict__ bo)
{
    int tid = blockIdx.x * blockDim.x + threadIdx.x;
    int total = BB * DD;
    for (int i = tid; i < total; i += gridDim.x * blockDim.x) {
        int b = i / DD;
        int d = i % DD;
        int src0 = 0 * BS * DD + (b >> 2) * DD + d;
        int src1 = 1 * BS * DD + (b >> 2) * DD + d;
        h0s[i] = h0[src0];
        c0s[i] = c0[src0];
        h1s[i] = h0[src1];
        c1s[i] = c0[src1];
    }
    if (tid < BB) {
        tokens[tid] = inputs[tid >> 2];
        pidx[tid]   = tid;
        fin[tid]    = 0;
        lp[tid]     = 0.0f;
        bo[0 * BB + tid] = inputs[tid >> 2];
        for (int r = 1; r <= TSTEPS; r++) bo[r * BB + tid] = 0;
    }
}

// ---------------------------------------------------------------- LSTM: one block per output unit j
// 512 blocks x 256 threads; thread = (b 0..63, gate 0..3).
// W chunk staged into LDS via coalesced cooperative load (fixes 72 GB/s broadcast-fetch bound);
// inner loop reads Wl[g][kk] as wave-uniform LDS broadcast. Accumulation order unchanged
// from the passing R9 kernel -> bitwise-identical output.
__global__ __launch_bounds__(256) void lstm_kernel(
    const float* __restrict__ xbase, const int* __restrict__ xrow,
    const float* __restrict__ hsrc,  const float* __restrict__ csrc,
    const int* __restrict__ prow,
    float* __restrict__ hdst, float* __restrict__ cdst,
    const float* __restrict__ Wih, const float* __restrict__ Whh,
    const float* __restrict__ bias)
{
    __shared__ float U[64][129];   // [b][k]: bank (b+k)%32, 2-way max (free)
    __shared__ float Wl[4][128];   // staged weight chunk, read as wave-uniform broadcast
    __shared__ double Z[4][64];
    __shared__ int rows_s[64], prows_s[64];
    int tid = threadIdx.x;
    int j = blockIdx.x;
    int b = tid & 63;
    int g = tid >> 6;

    if (tid < 64) {
        rows_s[tid]  = xrow ? xrow[tid] : tid;
        prows_s[tid] = prow[tid];
    }
    __syncthreads();

    double a0 = 0.0, a1 = 0.0, a2 = 0.0, a3 = 0.0;   // ILP-4 chains (kk%4)
    for (int ch = 0; ch < 8; ch++) {
        int k0 = ch * 128;
        __syncthreads();
        #pragma unroll
        for (int i = 0; i < 32; i++) {          // 64x128 cooperative U stage
            int e = tid + i * 256;
            int kk = e & 127, bb = e >> 7;
            float v;
            if (k0 < 512) v = xbase[(size_t)rows_s[bb] * DD + k0 + kk];
            else          v = hsrc[(size_t)prows_s[bb] * DD + (k0 - 512) + kk];
            U[bb][kk] = v;
        }
        {   // coalesced W stage: 4 gates x 128 k (2 KB), consecutive lanes -> consecutive k
            const float* Wc = (k0 < 512) ? Wih : Whh;
            int kof = (k0 < 512) ? k0 : (k0 - 512);
            #pragma unroll
            for (int i = 0; i < 2; i++) {
                int e = tid + i * 256;
                int gg = e >> 7, kk = e & 127;
                Wl[gg][kk] = Wc[(size_t)(gg * DD + j) * DD + kof + kk];
            }
        }
        __syncthreads();
        #pragma unroll 8
        for (int kk = 0; kk < 128; kk += 4) {
            a0 = fma((double)U[b][kk + 0], (double)Wl[g][kk + 0], a0);
            a1 = fma((double)U[b][kk + 1], (double)Wl[g][kk + 1], a1);
            a2 = fma((double)U[b][kk + 2], (double)Wl[g][kk + 2], a2);
            a3 = fma((double)U[b][kk + 3], (double)Wl[g][kk + 3], a3);
        }
    }
    Z[g][b] = ((a0 + a1) + (a2 + a3));
    __syncthreads();

    if (tid < 64) {
        double zi = Z[0][b] + (double)bias[0 * DD + j];
        double zf = Z[1][b] + (double)bias[1 * DD + j];
        double zg = Z[2][b] + (double)bias[2 * DD + j];
        double zo = Z[3][b] + (double)bias[3 * DD + j];
        double si = 1.0 / (1.0 + exp(-zi));
        double sf = 1.0 / (1.0 + exp(-zf));
        double so = 1.0 / (1.0 + exp(-zo));
        double cold = (double)csrc[(size_t)prows_s[b] * DD + j];
        double cn = sf * cold + si * tanh(zg);
        double hn = so * tanh(cn);
        hdst[b * DD + j] = (float)hn;   // fp32 boundary
        cdst[b * DD + j] = (float)cn;
    }
}

// ---------------------------------------------------------------- projection GEMM, K-split x2
__global__ __launch_bounds__(256) void proj_kernel(
    const float* __restrict__ h1, const float* __restrict__ Wp,
    double* __restrict__ pp)
{
    __shared__ float sh[64][68];    // [b][k-chunk]
    __shared__ float sw[64][68];    // [k-chunk][v]
    int vtile = blockIdx.x % NVT;
    int kh    = blockIdx.x / NVT;   // 0 or 1
    int kbase = kh * 256;
    int vbase = vtile * VT;
    int tid = threadIdx.x;
    int b0 = (tid >> 4) * 4;
    int v0 = (tid & 15) * 4;

    double acc[4][4];
    #pragma unroll
    for (int i = 0; i < 4; i++)
        #pragma unroll
        for (int q = 0; q < 4; q++) acc[i][q] = 0.0;

    for (int ch = 0; ch < 4; ch++) {
        int k0 = kbase + ch * 64;
        __syncthreads();
        #pragma unroll
        for (int i = 0; i < 16; i++) {
            int e = tid + i * 256;
            int bb = e >> 6, kk = e & 63;
            sh[bb][kk] = h1[bb * DD + k0 + kk];
        }
        #pragma unroll
        for (int i = 0; i < 16; i++) {
            int e = tid + i * 256;
            int kk = e >> 6, vv = e & 63;
            sw[kk][vv] = Wp[(size_t)(k0 + kk) * VV + vbase + vv];
        }
        __syncthreads();
        #pragma unroll
        for (int k4 = 0; k4 < 16; k4++) {
            int k = k4 * 4;
            float4 h4[4], w4[4];
            #pragma unroll
            for (int i = 0; i < 4; i++) h4[i] = *(const float4*)&sh[b0 + i][k];
            #pragma unroll
            for (int kk = 0; kk < 4; kk++) w4[kk] = *(const float4*)&sw[k + kk][v0];
            #pragma unroll
            for (int i = 0; i < 4; i++) {
                const float hh[4] = {h4[i].x, h4[i].y, h4[i].z, h4[i].w};
                #pragma unroll
                for (int kk = 0; kk < 4; kk++) {
                    double hd = (double)hh[kk];
                    const float ww[4] = {w4[kk].x, w4[kk].y, w4[kk].z, w4[kk].w};
                    #pragma unroll
                    for (int q = 0; q < 4; q++)
                        acc[i][q] = fma(hd, (double)ww[q], acc[i][q]);
                }
            }
        }
    }

    double* base = pp + (size_t)kh * BB * VV;
    #pragma unroll
    for (int i = 0; i < 4; i++)
        #pragma unroll
        for (int q = 0; q < 4; q++)
            base[(size_t)(b0 + i) * VV + vbase + v0 + q] = acc[i][q];
}

// ---------------------------------------------------------------- fused reduce + LSE + row top-4
// 64 blocks x 1024 threads. Pass1: z=fp32((pp0+pp1)+bias), write logits, cache in regs.
#define NPT 32   // ceil(32000/1024)
__global__ __launch_bounds__(1024) void row_kernel(
    const double* __restrict__ pp, const float* __restrict__ bp,
    float* __restrict__ outf, const float* __restrict__ lp,
    const int* __restrict__ fin,
    float* __restrict__ rcv, int* __restrict__ rci, int step0)
{
    int row = blockIdx.x;
    int j   = row & 3;
    int tid = threadIdx.x;
    int base_idx = j * VV;

    const double* p0 = pp + (size_t)row * VV;
    const double* p1 = pp + (size_t)BB * VV + (size_t)row * VV;
    float* xo = outf + (size_t)row * VV;

    __shared__ double red[1024];

    // ---- pass 1: compute fp32 logits, write, cache, max
    float zreg[NPT];
    double m = -1e300;
    #pragma unroll
    for (int q = 0; q < NPT; q++) {
        int i = tid + q * 1024;
        float zf = 0.0f;
        if (i < VV) {
            double z = (p0[i] + p1[i]) + (double)bp[i];
            zf = (float)z;                 // fp32 boundary
            xo[i] = zf;
            m = fmax(m, (double)zf);
        }
        zreg[q] = zf;
    }

    float lp_r = step0 ? 0.0f : lp[row];
    int   f    = step0 ? 0    : fin[row];
    if (step0 && j != 0) {
        if (tid < 4) { rcv[row * 4 + tid] = NEGF; rci[row * 4 + tid] = base_idx + tid; }
        return;
    }
    if (f) {
        if (tid < 4) {
            rcv[row * 4 + tid] = (tid == 0) ? lp_r : NEGF;
            rci[row * 4 + tid] = base_idx + tid;
        }
        return;
    }

    red[tid] = m; __syncthreads();
    for (int s = 512; s > 0; s >>= 1) {
        if (tid < s) red[tid] = fmax(red[tid], red[tid + s]);
        __syncthreads();
    }
    m = red[0];
    __syncthreads();

    // ---- pass 2: sumexp from registers
    double sum = 0.0;
    #pragma unroll
    for (int q = 0; q < NPT; q++) {
        int i = tid + q * 1024;
        if (i < VV) sum += exp((double)zreg[q] - m);
    }
    red[tid] = sum; __syncthreads();
    for (int s = 512; s > 0; s >>= 1) {
        if (tid < s) red[tid] += red[tid + s];
        __syncthreads();
    }
    double lse = m + log(red[0]);
    __syncthreads();

    // ---- pass 3: per-thread top-4 from registers
    float bv[4]; int bx[4];
    #pragma unroll
    for (int q = 0; q < 4; q++) { bv[q] = -3.4e38f; bx[q] = 0x7fffffff; }
    #pragma unroll
    for (int q = 0; q < NPT; q++) {
        int i = tid + q * 1024;
        if (i < VV) {
            float lgp32 = (float)((double)zreg[q] - lse);
            float val   = (float)((double)lp_r + (double)lgp32);
            int idx = base_idx + i;
            if (better(val, idx, bv[3], bx[3])) {
                bv[3] = val; bx[3] = idx;
                #pragma unroll
                for (int s = 3; s > 0; s--) {
                    if (better(bv[s], bx[s], bv[s - 1], bx[s - 1])) {
                        float tv2 = bv[s]; bv[s] = bv[s - 1]; bv[s - 1] = tv2;
                        int ti2 = bx[s]; bx[s] = bx[s - 1]; bx[s - 1] = ti2;
                    }
                }
            }
        }
    }

    __shared__ float sv[1024][4];
    __shared__ int   si_[1024][4];
    #pragma unroll
    for (int q = 0; q < 4; q++) { sv[tid][q] = bv[q]; si_[tid][q] = bx[q]; }
    __syncthreads();
    for (int s = 512; s > 0; s >>= 1) {
        if (tid < s) {
            float av[4], ov[4], mv[4]; int ai[4], oi[4], mi[4];
            #pragma unroll
            for (int q = 0; q < 4; q++) {
                av[q] = sv[tid][q];     ai[q] = si_[tid][q];
                ov[q] = sv[tid + s][q]; oi[q] = si_[tid + s][q];
            }
            int pa = 0, pb = 0;
            #pragma unroll
            for (int q = 0; q < 4; q++) {
                bool takeA = (pb >= 4) || (pa < 4 && better(av[pa], ai[pa], ov[pb], oi[pb]));
                if (takeA) { mv[q] = av[pa]; mi[q] = ai[pa]; pa++; }
                else       { mv[q] = ov[pb]; mi[q] = oi[pb]; pb++; }
            }
            #pragma unroll
            for (int q = 0; q < 4; q++) { sv[tid][q] = mv[q]; si_[tid][q] = mi[q]; }
        }
        __syncthreads();
    }
    if (tid < 4) {
        rcv[row * 4 + tid] = sv[0][tid];
        rci[row * 4 + tid] = si_[0][tid];
    }
}

// ---------------------------------------------------------------- merge 16 candidates/batch + state update
__global__ void merge_update_kernel(
    const float* __restrict__ rcv, const int* __restrict__ rci,
    float* __restrict__ lp, int* __restrict__ fin,
    int* __restrict__ tokens, int* __restrict__ pidx,
    int* __restrict__ bo, int t)
{
    int b = threadIdx.x;           // 64
    int bi = b >> 2, r = b & 3;

    float cv[16]; int ci[16];
    #pragma unroll
    for (int c = 0; c < 16; c++) { cv[c] = rcv[bi * 16 + c]; ci[c] = rci[bi * 16 + c]; }

    int sel = 0;
    #pragma unroll
    for (int c = 0; c < 16; c++) {
        int rank = 0;
        #pragma unroll
        for (int d = 0; d < 16; d++)
            if (d != c && better(cv[d], ci[d], cv[c], ci[c])) rank++;
        if (rank == r) sel = c;
    }

    float v = cv[sel];
    int flat = ci[sel];
    int q = flat / VV;
    int p = q + bi * 4;
    int tok = flat - q * VV;
    int oldfin = fin[p];
    int col[TSTEPS + 1];
    #pragma unroll
    for (int rr = 0; rr <= TSTEPS; rr++) col[rr] = bo[rr * BB + p];
    __syncthreads();
    #pragma unroll
    for (int rr = 0; rr <= TSTEPS; rr++) bo[rr * BB + b] = col[rr];
    bo[(t + 1) * BB + b] = tok;
    fin[b]    = oldfin | (tok == EOSTOK);
    lp[b]     = v;
    tokens[b] = tok;
    pidx[b]   = p;
}

// ---------------------------------------------------------------- final beam_out -> float
__global__ void final_kernel(const int* __restrict__ bo, float* __restrict__ out)
{
    int i = blockIdx.x * blockDim.x + threadIdx.x;
    if (i < (TSTEPS + 1) * BB) out[i] = (float)bo[i];
}

// ---------------------------------------------------------------- host
extern "C" void kernel_launch(void* const* d_in, const int* in_sizes, int n_in,
                              void* d_out, int out_size, void* d_ws, size_t ws_size,
                              hipStream_t stream)
{
    const int*   inputs = (const int*)d_in[0];
    const float* h0   = (const float*)d_in[1];
    const float* c0   = (const float*)d_in[2];
    const float* emb  = (const float*)d_in[3];
    const float* Wih0 = (const float*)d_in[4];
    const float* Whh0 = (const float*)d_in[5];
    const float* b0   = (const float*)d_in[6];
    const float* Wih1 = (const float*)d_in[7];
    const float* Whh1 = (const float*)d_in[8];
    const float* b1   = (const float*)d_in[9];
    const float* Wp   = (const float*)d_in[10];
    const float* bp   = (const float*)d_in[11];
    float* out = (float*)d_out;

    char* w = (char*)d_ws;
    size_t off = 0;
    auto alloc = [&](size_t bytes) { void* p = w + off; off += (bytes + 255) & ~255ULL; return p; };
    double* pp = (double*)alloc((size_t)2 * BB * VV * 8);   // fp64 K-split partials
    float* h0s[2], *c0s[2], *h1s[2], *c1s[2];
    for (int s = 0; s < 2; s++) {
        h0s[s] = (float*)alloc(BB * DD * 4);
        c0s[s] = (float*)alloc(BB * DD * 4);
        h1s[s] = (float*)alloc(BB * DD * 4);
        c1s[s] = (float*)alloc(BB * DD * 4);
    }
    float* rcv   = (float*)alloc(BB * 4 * 4);
    int*   rci   = (int*)alloc(BB * 4 * 4);
    float* lp    = (float*)alloc(BB * 4);
    int* pidx    = (int*)alloc(BB * 4);
    int* tokens  = (int*)alloc(BB * 4);
    int* fin     = (int*)alloc(BB * 4);
    int* bo      = (int*)alloc((TSTEPS + 1) * BB * 4);

    init_kernel<<<128, 256, 0, stream>>>(inputs, h0, c0,
                                         h0s[0], c0s[0], h1s[0], c1s[0],
                                         tokens, pidx, fin, lp, bo);

    for (int t = 0; t < TSTEPS; t++) {
        int s = t & 1, d2 = s ^ 1;
        lstm_kernel<<<512, 256, 0, stream>>>(emb, tokens, h0s[s], c0s[s], pidx,
                                             h0s[d2], c0s[d2], Wih0, Whh0, b0);
        lstm_kernel<<<512, 256, 0, stream>>>(h0s[d2], nullptr, h1s[s], c1s[s], pidx,
                                             h1s[d2], c1s[d2], Wih1, Whh1, b1);

        float* outf = out + (size_t)t * BB * VV;
        proj_kernel<<<NVT * 2, 256, 0, stream>>>(h1s[d2], Wp, pp);
        row_kernel<<<BB, 1024, 0, stream>>>(pp, bp, outf, lp, fin, rcv, rci, t == 0 ? 1 : 0);
        merge_update_kernel<<<1, 64, 0, stream>>>(rcv, rci, lp, fin, tokens, pidx, bo, t);
    }
    final_kernel<<<5, 256, 0, stream>>>(bo, out + (size_t)TSTEPS * BB * VV);
}

// Round 11
// 4158.991 us; speedup vs baseline: 7.6942x; 1.0090x over previous
//
#include <hip/hip_runtime.h>
#include <math.h>

#define BS     16
#define NB     4
#define BB     64      // BS*NB
#define DD     512
#define VV     32000
#define TSTEPS 16
#define EOSTOK 2
#define NEGF   (-1e32f)
#define VT     64
#define NVT    (VV / VT)   // 500

__device__ __forceinline__ bool better(float av, int ai, float bv, int bi_) {
    return (av > bv) || (av == bv && ai < bi_);
}

// ---------------------------------------------------------------- init (fp32 states)
__global__ void init_kernel(const int* __restrict__ inputs,
                            const float* __restrict__ h0, const float* __restrict__ c0,
                            float* __restrict__ h0s, float* __restrict__ c0s,
                            float* __restrict__ h1s, float* __restrict__ c1s,
                            int* __restrict__ tokens, int* __restrict__ pidx,
                            int* __restrict__ fin, float* __restrict__ lp,
                            int* __restrict__ bo)
{
    int tid = blockIdx.x * blockDim.x + threadIdx.x;
    int total = BB * DD;
    for (int i = tid; i < total; i += gridDim.x * blockDim.x) {
        int b = i / DD;
        int d = i % DD;
        int src0 = 0 * BS * DD + (b >> 2) * DD + d;
        int src1 = 1 * BS * DD + (b >> 2) * DD + d;
        h0s[i] = h0[src0];
        c0s[i] = c0[src0];
        h1s[i] = h0[src1];
        c1s[i] = c0[src1];
    }
    if (tid < BB) {
        tokens[tid] = inputs[tid >> 2];
        pidx[tid]   = tid;
        fin[tid]    = 0;
        lp[tid]     = 0.0f;
        bo[0 * BB + tid] = inputs[tid >> 2];
        for (int r = 1; r <= TSTEPS; r++) bo[r * BB + tid] = 0;
    }
}

// ---------------------------------------------------------------- LSTM: one block per output unit j
// 512 blocks x 256 threads; thread = (b 0..63, gate 0..3).
// ALL weight rows (4 gates x 1024 K = 16 KB) staged in ONE up-front float4 burst:
// grid-wide 8 MB in flight -> BW-limited, not latency-limited. Inner FMA loop and
// accumulation order bitwise-identical to the passing R10 kernel.
__global__ __launch_bounds__(256) void lstm_kernel(
    const float* __restrict__ xbase, const int* __restrict__ xrow,
    const float* __restrict__ hsrc,  const float* __restrict__ csrc,
    const int* __restrict__ prow,
    float* __restrict__ hdst, float* __restrict__ cdst,
    const float* __restrict__ Wih, const float* __restrict__ Whh,
    const float* __restrict__ bias)
{
    __shared__ float U[64][129];    // [b][k]: bank (b+k)%32, 2-way max (free)
    __shared__ float Wl[4][1024];   // all weight rows for this j: [gate][k], k<512=Wih, k>=512=Whh
    __shared__ double Z[4][64];
    __shared__ int rows_s[64], prows_s[64];
    int tid = threadIdx.x;
    int j = blockIdx.x;
    int b = tid & 63;
    int g = tid >> 6;

    if (tid < 64) {
        rows_s[tid]  = xrow ? xrow[tid] : tid;
        prows_s[tid] = prow[tid];
    }
    // ---- one-shot weight stage: 1024 float4 (16 KB), 4 per thread, fully coalesced
    #pragma unroll
    for (int i = 0; i < 4; i++) {
        int e = tid + i * 256;          // 0..1023
        int r = e >> 7;                 // row 0..7
        int c = e & 127;                // float4 col within 512-float row
        int gg = r >> 1, hh = r & 1;    // gate, Wih/Whh half
        const float4* src = (const float4*)(hh ? Whh : Wih) + (size_t)(gg * DD + j) * 128 + c;
        ((float4*)Wl)[gg * 256 + hh * 128 + c] = *src;
    }

    double a0 = 0.0, a1 = 0.0, a2 = 0.0, a3 = 0.0;   // ILP-4 chains (kk%4)
    for (int ch = 0; ch < 8; ch++) {
        int k0 = ch * 128;
        __syncthreads();
        #pragma unroll
        for (int i = 0; i < 32; i++) {          // 64x128 cooperative U stage
            int e = tid + i * 256;
            int kk = e & 127, bb = e >> 7;
            float v;
            if (k0 < 512) v = xbase[(size_t)rows_s[bb] * DD + k0 + kk];
            else          v = hsrc[(size_t)prows_s[bb] * DD + (k0 - 512) + kk];
            U[bb][kk] = v;
        }
        __syncthreads();
        const float* Wrow = &Wl[g][k0];         // wave-uniform broadcast reads
        #pragma unroll 8
        for (int kk = 0; kk < 128; kk += 4) {
            a0 = fma((double)U[b][kk + 0], (double)Wrow[kk + 0], a0);
            a1 = fma((double)U[b][kk + 1], (double)Wrow[kk + 1], a1);
            a2 = fma((double)U[b][kk + 2], (double)Wrow[kk + 2], a2);
            a3 = fma((double)U[b][kk + 3], (double)Wrow[kk + 3], a3);
        }
    }
    Z[g][b] = ((a0 + a1) + (a2 + a3));
    __syncthreads();

    if (tid < 64) {
        double zi = Z[0][b] + (double)bias[0 * DD + j];
        double zf = Z[1][b] + (double)bias[1 * DD + j];
        double zg = Z[2][b] + (double)bias[2 * DD + j];
        double zo = Z[3][b] + (double)bias[3 * DD + j];
        double si = 1.0 / (1.0 + exp(-zi));
        double sf = 1.0 / (1.0 + exp(-zf));
        double so = 1.0 / (1.0 + exp(-zo));
        double cold = (double)csrc[(size_t)prows_s[b] * DD + j];
        double cn = sf * cold + si * tanh(zg);
        double hn = so * tanh(cn);
        hdst[b * DD + j] = (float)hn;   // fp32 boundary
        cdst[b * DD + j] = (float)cn;
    }
}

// ---------------------------------------------------------------- projection GEMM, K-split x2
__global__ __launch_bounds__(256) void proj_kernel(
    const float* __restrict__ h1, const float* __restrict__ Wp,
    double* __restrict__ pp)
{
    __shared__ float sh[64][68];    // [b][k-chunk]
    __shared__ float sw[64][68];    // [k-chunk][v]
    int vtile = blockIdx.x % NVT;
    int kh    = blockIdx.x / NVT;   // 0 or 1
    int kbase = kh * 256;
    int vbase = vtile * VT;
    int tid = threadIdx.x;
    int b0 = (tid >> 4) * 4;
    int v0 = (tid & 15) * 4;

    double acc[4][4];
    #pragma unroll
    for (int i = 0; i < 4; i++)
        #pragma unroll
        for (int q = 0; q < 4; q++) acc[i][q] = 0.0;

    for (int ch = 0; ch < 4; ch++) {
        int k0 = kbase + ch * 64;
        __syncthreads();
        #pragma unroll
        for (int i = 0; i < 16; i++) {
            int e = tid + i * 256;
            int bb = e >> 6, kk = e & 63;
            sh[bb][kk] = h1[bb * DD + k0 + kk];
        }
        #pragma unroll
        for (int i = 0; i < 16; i++) {
            int e = tid + i * 256;
            int kk = e >> 6, vv = e & 63;
            sw[kk][vv] = Wp[(size_t)(k0 + kk) * VV + vbase + vv];
        }
        __syncthreads();
        #pragma unroll
        for (int k4 = 0; k4 < 16; k4++) {
            int k = k4 * 4;
            float4 h4[4], w4[4];
            #pragma unroll
            for (int i = 0; i < 4; i++) h4[i] = *(const float4*)&sh[b0 + i][k];
            #pragma unroll
            for (int kk = 0; kk < 4; kk++) w4[kk] = *(const float4*)&sw[k + kk][v0];
            #pragma unroll
            for (int i = 0; i < 4; i++) {
                const float hh[4] = {h4[i].x, h4[i].y, h4[i].z, h4[i].w};
                #pragma unroll
                for (int kk = 0; kk < 4; kk++) {
                    double hd = (double)hh[kk];
                    const float ww[4] = {w4[kk].x, w4[kk].y, w4[kk].z, w4[kk].w};
                    #pragma unroll
                    for (int q = 0; q < 4; q++)
                        acc[i][q] = fma(hd, (double)ww[q], acc[i][q]);
                }
            }
        }
    }

    double* base = pp + (size_t)kh * BB * VV;
    #pragma unroll
    for (int i = 0; i < 4; i++)
        #pragma unroll
        for (int q = 0; q < 4; q++)
            base[(size_t)(b0 + i) * VV + vbase + v0 + q] = acc[i][q];
}

// ---------------------------------------------------------------- fused reduce + LSE + row top-4
// 64 blocks x 1024 threads. Pass1: z=fp32((pp0+pp1)+bias), write logits, cache in regs.
#define NPT 32   // ceil(32000/1024)
__global__ __launch_bounds__(1024) void row_kernel(
    const double* __restrict__ pp, const float* __restrict__ bp,
    float* __restrict__ outf, const float* __restrict__ lp,
    const int* __restrict__ fin,
    float* __restrict__ rcv, int* __restrict__ rci, int step0)
{
    int row = blockIdx.x;
    int j   = row & 3;
    int tid = threadIdx.x;
    int base_idx = j * VV;

    const double* p0 = pp + (size_t)row * VV;
    const double* p1 = pp + (size_t)BB * VV + (size_t)row * VV;
    float* xo = outf + (size_t)row * VV;

    __shared__ double red[1024];

    // ---- pass 1: compute fp32 logits, write, cache, max
    float zreg[NPT];
    double m = -1e300;
    #pragma unroll
    for (int q = 0; q < NPT; q++) {
        int i = tid + q * 1024;
        float zf = 0.0f;
        if (i < VV) {
            double z = (p0[i] + p1[i]) + (double)bp[i];
            zf = (float)z;                 // fp32 boundary
            xo[i] = zf;
            m = fmax(m, (double)zf);
        }
        zreg[q] = zf;
    }

    float lp_r = step0 ? 0.0f : lp[row];
    int   f    = step0 ? 0    : fin[row];
    if (step0 && j != 0) {
        if (tid < 4) { rcv[row * 4 + tid] = NEGF; rci[row * 4 + tid] = base_idx + tid; }
        return;
    }
    if (f) {
        if (tid < 4) {
            rcv[row * 4 + tid] = (tid == 0) ? lp_r : NEGF;
            rci[row * 4 + tid] = base_idx + tid;
        }
        return;
    }

    red[tid] = m; __syncthreads();
    for (int s = 512; s > 0; s >>= 1) {
        if (tid < s) red[tid] = fmax(red[tid], red[tid + s]);
        __syncthreads();
    }
    m = red[0];
    __syncthreads();

    // ---- pass 2: sumexp from registers
    double sum = 0.0;
    #pragma unroll
    for (int q = 0; q < NPT; q++) {
        int i = tid + q * 1024;
        if (i < VV) sum += exp((double)zreg[q] - m);
    }
    red[tid] = sum; __syncthreads();
    for (int s = 512; s > 0; s >>= 1) {
        if (tid < s) red[tid] += red[tid + s];
        __syncthreads();
    }
    double lse = m + log(red[0]);
    __syncthreads();

    // ---- pass 3: per-thread top-4 from registers
    float bv[4]; int bx[4];
    #pragma unroll
    for (int q = 0; q < 4; q++) { bv[q] = -3.4e38f; bx[q] = 0x7fffffff; }
    #pragma unroll
    for (int q = 0; q < NPT; q++) {
        int i = tid + q * 1024;
        if (i < VV) {
            float lgp32 = (float)((double)zreg[q] - lse);
            float val   = (float)((double)lp_r + (double)lgp32);
            int idx = base_idx + i;
            if (better(val, idx, bv[3], bx[3])) {
                bv[3] = val; bx[3] = idx;
                #pragma unroll
                for (int s = 3; s > 0; s--) {
                    if (better(bv[s], bx[s], bv[s - 1], bx[s - 1])) {
                        float tv2 = bv[s]; bv[s] = bv[s - 1]; bv[s - 1] = tv2;
                        int ti2 = bx[s]; bx[s] = bx[s - 1]; bx[s - 1] = ti2;
                    }
                }
            }
        }
    }

    __shared__ float sv[1024][4];
    __shared__ int   si_[1024][4];
    #pragma unroll
    for (int q = 0; q < 4; q++) { sv[tid][q] = bv[q]; si_[tid][q] = bx[q]; }
    __syncthreads();
    for (int s = 512; s > 0; s >>= 1) {
        if (tid < s) {
            float av[4], ov[4], mv[4]; int ai[4], oi[4], mi[4];
            #pragma unroll
            for (int q = 0; q < 4; q++) {
                av[q] = sv[tid][q];     ai[q] = si_[tid][q];
                ov[q] = sv[tid + s][q]; oi[q] = si_[tid + s][q];
            }
            int pa = 0, pb = 0;
            #pragma unroll
            for (int q = 0; q < 4; q++) {
                bool takeA = (pb >= 4) || (pa < 4 && better(av[pa], ai[pa], ov[pb], oi[pb]));
                if (takeA) { mv[q] = av[pa]; mi[q] = ai[pa]; pa++; }
                else       { mv[q] = ov[pb]; mi[q] = oi[pb]; pb++; }
            }
            #pragma unroll
            for (int q = 0; q < 4; q++) { sv[tid][q] = mv[q]; si_[tid][q] = mi[q]; }
        }
        __syncthreads();
    }
    if (tid < 4) {
        rcv[row * 4 + tid] = sv[0][tid];
        rci[row * 4 + tid] = si_[0][tid];
    }
}

// ---------------------------------------------------------------- merge 16 candidates/batch + state update
__global__ void merge_update_kernel(
    const float* __restrict__ rcv, const int* __restrict__ rci,
    float* __restrict__ lp, int* __restrict__ fin,
    int* __restrict__ tokens, int* __restrict__ pidx,
    int* __restrict__ bo, int t)
{
    int b = threadIdx.x;           // 64
    int bi = b >> 2, r = b & 3;

    float cv[16]; int ci[16];
    #pragma unroll
    for (int c = 0; c < 16; c++) { cv[c] = rcv[bi * 16 + c]; ci[c] = rci[bi * 16 + c]; }

    int sel = 0;
    #pragma unroll
    for (int c = 0; c < 16; c++) {
        int rank = 0;
        #pragma unroll
        for (int d = 0; d < 16; d++)
            if (d != c && better(cv[d], ci[d], cv[c], ci[c])) rank++;
        if (rank == r) sel = c;
    }

    float v = cv[sel];
    int flat = ci[sel];
    int q = flat / VV;
    int p = q + bi * 4;
    int tok = flat - q * VV;
    int oldfin = fin[p];
    int col[TSTEPS + 1];
    #pragma unroll
    for (int rr = 0; rr <= TSTEPS; rr++) col[rr] = bo[rr * BB + p];
    __syncthreads();
    #pragma unroll
    for (int rr = 0; rr <= TSTEPS; rr++) bo[rr * BB + b] = col[rr];
    bo[(t + 1) * BB + b] = tok;
    fin[b]    = oldfin | (tok == EOSTOK);
    lp[b]     = v;
    tokens[b] = tok;
    pidx[b]   = p;
}

// ---------------------------------------------------------------- final beam_out -> float
__global__ void final_kernel(const int* __restrict__ bo, float* __restrict__ out)
{
    int i = blockIdx.x * blockDim.x + threadIdx.x;
    if (i < (TSTEPS + 1) * BB) out[i] = (float)bo[i];
}

// ---------------------------------------------------------------- host
extern "C" void kernel_launch(void* const* d_in, const int* in_sizes, int n_in,
                              void* d_out, int out_size, void* d_ws, size_t ws_size,
                              hipStream_t stream)
{
    const int*   inputs = (const int*)d_in[0];
    const float* h0   = (const float*)d_in[1];
    const float* c0   = (const float*)d_in[2];
    const float* emb  = (const float*)d_in[3];
    const float* Wih0 = (const float*)d_in[4];
    const float* Whh0 = (const float*)d_in[5];
    const float* b0   = (const float*)d_in[6];
    const float* Wih1 = (const float*)d_in[7];
    const float* Whh1 = (const float*)d_in[8];
    const float* b1   = (const float*)d_in[9];
    const float* Wp   = (const float*)d_in[10];
    const float* bp   = (const float*)d_in[11];
    float* out = (float*)d_out;

    char* w = (char*)d_ws;
    size_t off = 0;
    auto alloc = [&](size_t bytes) { void* p = w + off; off += (bytes + 255) & ~255ULL; return p; };
    double* pp = (double*)alloc((size_t)2 * BB * VV * 8);   // fp64 K-split partials
    float* h0s[2], *c0s[2], *h1s[2], *c1s[2];
    for (int s = 0; s < 2; s++) {
        h0s[s] = (float*)alloc(BB * DD * 4);
        c0s[s] = (float*)alloc(BB * DD * 4);
        h1s[s] = (float*)alloc(BB * DD * 4);
        c1s[s] = (float*)alloc(BB * DD * 4);
    }
    float* rcv   = (float*)alloc(BB * 4 * 4);
    int*   rci   = (int*)alloc(BB * 4 * 4);
    float* lp    = (float*)alloc(BB * 4);
    int* pidx    = (int*)alloc(BB * 4);
    int* tokens  = (int*)alloc(BB * 4);
    int* fin     = (int*)alloc(BB * 4);
    int* bo      = (int*)alloc((TSTEPS + 1) * BB * 4);

    init_kernel<<<128, 256, 0, stream>>>(inputs, h0, c0,
                                         h0s[0], c0s[0], h1s[0], c1s[0],
                                         tokens, pidx, fin, lp, bo);

    for (int t = 0; t < TSTEPS; t++) {
        int s = t & 1, d2 = s ^ 1;
        lstm_kernel<<<512, 256, 0, stream>>>(emb, tokens, h0s[s], c0s[s], pidx,
                                             h0s[d2], c0s[d2], Wih0, Whh0, b0);
        lstm_kernel<<<512, 256, 0, stream>>>(h0s[d2], nullptr, h1s[s], c1s[s], pidx,
                                             h1s[d2], c1s[d2], Wih1, Whh1, b1);

        float* outf = out + (size_t)t * BB * VV;
        proj_kernel<<<NVT * 2, 256, 0, stream>>>(h1s[d2], Wp, pp);
        row_kernel<<<BB, 1024, 0, stream>>>(pp, bp, outf, lp, fin, rcv, rci, t == 0 ? 1 : 0);
        merge_update_kernel<<<1, 64, 0, stream>>>(rcv, rci, lp, fin, tokens, pidx, bo, t);
    }
    final_kernel<<<5, 256, 0, stream>>>(bo, out + (size_t)TSTEPS * BB * VV);
}

// Round 12
// 3061.079 us; speedup vs baseline: 10.4539x; 1.3587x over previous
//
#include <hip/hip_runtime.h>
#include <math.h>

#define BS     16
#define NB     4
#define BB     64      // BS*NB
#define DD     512
#define VV     32000
#define TSTEPS 16
#define EOSTOK 2
#define NEGF   (-1e32f)
#define VT     64
#define NVT    (VV / VT)   // 500

__device__ __forceinline__ bool better(float av, int ai, float bv, int bi_) {
    return (av > bv) || (av == bv && ai < bi_);
}

// async global->LDS staging, no VGPR round-trip (gfx950)
__device__ __forceinline__ void glds4(const float* src, float* dst) {
    __builtin_amdgcn_global_load_lds((const __attribute__((address_space(1))) void*)src,
                                     (__attribute__((address_space(3))) void*)dst, 4, 0, 0);
}
__device__ __forceinline__ void glds16(const float* src, float* dst) {
    __builtin_amdgcn_global_load_lds((const __attribute__((address_space(1))) void*)src,
                                     (__attribute__((address_space(3))) void*)dst, 16, 0, 0);
}

// ---------------------------------------------------------------- init (fp32 states)
__global__ void init_kernel(const int* __restrict__ inputs,
                            const float* __restrict__ h0, const float* __restrict__ c0,
                            float* __restrict__ h0s, float* __restrict__ c0s,
                            float* __restrict__ h1s, float* __restrict__ c1s,
                            int* __restrict__ tokens, int* __restrict__ pidx,
                            int* __restrict__ fin, float* __restrict__ lp,
                            int* __restrict__ bo)
{
    int tid = blockIdx.x * blockDim.x + threadIdx.x;
    int total = BB * DD;
    for (int i = tid; i < total; i += gridDim.x * blockDim.x) {
        int b = i / DD;
        int d = i % DD;
        int src0 = 0 * BS * DD + (b >> 2) * DD + d;
        int src1 = 1 * BS * DD + (b >> 2) * DD + d;
        h0s[i] = h0[src0];
        c0s[i] = c0[src0];
        h1s[i] = h0[src1];
        c1s[i] = c0[src1];
    }
    if (tid < BB) {
        tokens[tid] = inputs[tid >> 2];
        pidx[tid]   = tid;
        fin[tid]    = 0;
        lp[tid]     = 0.0f;
        bo[0 * BB + tid] = inputs[tid >> 2];
        for (int r = 1; r <= TSTEPS; r++) bo[r * BB + tid] = 0;
    }
}

// ---------------------------------------------------------------- LSTM: one block per output unit j
// 512 blocks x 256 threads; thread = (b 0..63, gate 0..3).
// ALL staging via global_load_lds (async, no VGPR round-trip): per-wave staging
// instructions issue back-to-back, one vmcnt drain at the barrier.
// FMA order bitwise-identical to the passing R11 kernel.
__global__ __launch_bounds__(256) void lstm_kernel(
    const float* __restrict__ xbase, const int* __restrict__ xrow,
    const float* __restrict__ hsrc,  const float* __restrict__ csrc,
    const int* __restrict__ prow,
    float* __restrict__ hdst, float* __restrict__ cdst,
    const float* __restrict__ Wih, const float* __restrict__ Whh,
    const float* __restrict__ bias)
{
    __shared__ float U[64][129];    // [b][k]: bank (b+k)%32; each wave-instr writes 256B inside one row
    __shared__ float Wl[4][1024];   // all weight rows for this j (16 KB), contiguous
    __shared__ double Z[4][64];
    __shared__ int rows_s[64], prows_s[64];
    int tid = threadIdx.x;
    int j = blockIdx.x;
    int b = tid & 63;
    int g = tid >> 6;
    int lane = tid & 63;
    int w = tid >> 6;               // wave id 0..3

    // ---- W burst: 16 KB via width-16 async copies (4 per thread), fully concurrent
    #pragma unroll
    for (int i = 0; i < 4; i++) {
        int s0 = i * 256 + w * 64;              // wave-uniform float4 slot base (0..1023)
        int gg = s0 >> 8;                       // gate
        int hh = (s0 >> 7) & 1;                 // 0 = Wih half, 1 = Whh half
        int c0 = s0 & 127;                      // float4 col within the 512-float row
        const float* rowbase = (hh ? Whh : Wih) + (size_t)(gg * DD + j) * DD;
        glds16(rowbase + 4 * (c0 + lane), (float*)Wl + 4 * s0);
    }
    if (tid < 64) {
        rows_s[tid]  = xrow ? xrow[tid] : tid;
        prows_s[tid] = prow[tid];
    }

    double a0 = 0.0, a1 = 0.0, a2 = 0.0, a3 = 0.0;   // ILP-4 chains (kk%4)
    for (int ch = 0; ch < 8; ch++) {
        int k0 = ch * 128;
        __syncthreads();    // prev chunk's readers done; rows_s visible (first iter)
        #pragma unroll
        for (int i = 0; i < 32; i++) {          // async U stage: 64x128, 256B per wave-instr
            int e0 = i * 256 + w * 64;          // wave-uniform
            int bb = e0 >> 7;                   // row (constant per wave-instr)
            int kk0 = e0 & 127;                 // 0 or 64
            const float* src;
            if (k0 < 512) src = xbase + (size_t)rows_s[bb] * DD + k0 + kk0 + lane;
            else          src = hsrc + (size_t)prows_s[bb] * DD + (k0 - 512) + kk0 + lane;
            glds4(src, &U[bb][kk0]);
        }
        __syncthreads();    // compiler drains vmcnt before s_barrier -> LDS writes landed
        const float* Wrow = &Wl[g][k0];         // wave-uniform broadcast reads
        #pragma unroll 8
        for (int kk = 0; kk < 128; kk += 4) {
            a0 = fma((double)U[b][kk + 0], (double)Wrow[kk + 0], a0);
            a1 = fma((double)U[b][kk + 1], (double)Wrow[kk + 1], a1);
            a2 = fma((double)U[b][kk + 2], (double)Wrow[kk + 2], a2);
            a3 = fma((double)U[b][kk + 3], (double)Wrow[kk + 3], a3);
        }
    }
    Z[g][b] = ((a0 + a1) + (a2 + a3));
    __syncthreads();

    if (tid < 64) {
        double zi = Z[0][b] + (double)bias[0 * DD + j];
        double zf = Z[1][b] + (double)bias[1 * DD + j];
        double zg = Z[2][b] + (double)bias[2 * DD + j];
        double zo = Z[3][b] + (double)bias[3 * DD + j];
        double si = 1.0 / (1.0 + exp(-zi));
        double sf = 1.0 / (1.0 + exp(-zf));
        double so = 1.0 / (1.0 + exp(-zo));
        double cold = (double)csrc[(size_t)prows_s[b] * DD + j];
        double cn = sf * cold + si * tanh(zg);
        double hn = so * tanh(cn);
        hdst[b * DD + j] = (float)hn;   // fp32 boundary
        cdst[b * DD + j] = (float)cn;
    }
}

// ---------------------------------------------------------------- projection GEMM, K-split x2
// Staging via global_load_lds (async). FMA order bitwise-identical to R11.
__global__ __launch_bounds__(256) void proj_kernel(
    const float* __restrict__ h1, const float* __restrict__ Wp,
    double* __restrict__ pp)
{
    __shared__ float sh[64][68];    // [b][k-chunk]; wave-instr writes 256B at row start
    __shared__ float sw[64][68];    // [k-chunk][v]
    int vtile = blockIdx.x % NVT;
    int kh    = blockIdx.x / NVT;   // 0 or 1
    int kbase = kh * 256;
    int vbase = vtile * VT;
    int tid = threadIdx.x;
    int lane = tid & 63;
    int w = tid >> 6;
    int b0 = (tid >> 4) * 4;
    int v0 = (tid & 15) * 4;

    double acc[4][4];
    #pragma unroll
    for (int i = 0; i < 4; i++)
        #pragma unroll
        for (int q = 0; q < 4; q++) acc[i][q] = 0.0;

    for (int ch = 0; ch < 4; ch++) {
        int k0 = kbase + ch * 64;
        __syncthreads();
        #pragma unroll
        for (int i = 0; i < 16; i++) {          // sh: row bb = i*4+w, cols 0..63
            int bb = i * 4 + w;
            glds4(h1 + (size_t)bb * DD + k0 + lane, &sh[bb][0]);
        }
        #pragma unroll
        for (int i = 0; i < 16; i++) {          // sw: row kk = i*4+w, cols 0..63
            int kk = i * 4 + w;
            glds4(Wp + (size_t)(k0 + kk) * VV + vbase + lane, &sw[kk][0]);
        }
        __syncthreads();
        #pragma unroll
        for (int k4 = 0; k4 < 16; k4++) {
            int k = k4 * 4;
            float4 h4[4], w4[4];
            #pragma unroll
            for (int i = 0; i < 4; i++) h4[i] = *(const float4*)&sh[b0 + i][k];
            #pragma unroll
            for (int kk = 0; kk < 4; kk++) w4[kk] = *(const float4*)&sw[k + kk][v0];
            #pragma unroll
            for (int i = 0; i < 4; i++) {
                const float hh[4] = {h4[i].x, h4[i].y, h4[i].z, h4[i].w};
                #pragma unroll
                for (int kk = 0; kk < 4; kk++) {
                    double hd = (double)hh[kk];
                    const float ww[4] = {w4[kk].x, w4[kk].y, w4[kk].z, w4[kk].w};
                    #pragma unroll
                    for (int q = 0; q < 4; q++)
                        acc[i][q] = fma(hd, (double)ww[q], acc[i][q]);
                }
            }
        }
    }

    double* base = pp + (size_t)kh * BB * VV;
    #pragma unroll
    for (int i = 0; i < 4; i++)
        #pragma unroll
        for (int q = 0; q < 4; q++)
            base[(size_t)(b0 + i) * VV + vbase + v0 + q] = acc[i][q];
}

// ---------------------------------------------------------------- fused reduce + LSE + row top-4
#define NPT 32   // ceil(32000/1024)
__global__ __launch_bounds__(1024) void row_kernel(
    const double* __restrict__ pp, const float* __restrict__ bp,
    float* __restrict__ outf, const float* __restrict__ lp,
    const int* __restrict__ fin,
    float* __restrict__ rcv, int* __restrict__ rci, int step0)
{
    int row = blockIdx.x;
    int j   = row & 3;
    int tid = threadIdx.x;
    int base_idx = j * VV;

    const double* p0 = pp + (size_t)row * VV;
    const double* p1 = pp + (size_t)BB * VV + (size_t)row * VV;
    float* xo = outf + (size_t)row * VV;

    __shared__ double red[1024];

    // ---- pass 1: compute fp32 logits, write, cache, max
    float zreg[NPT];
    double m = -1e300;
    #pragma unroll
    for (int q = 0; q < NPT; q++) {
        int i = tid + q * 1024;
        float zf = 0.0f;
        if (i < VV) {
            double z = (p0[i] + p1[i]) + (double)bp[i];
            zf = (float)z;                 // fp32 boundary
            xo[i] = zf;
            m = fmax(m, (double)zf);
        }
        zreg[q] = zf;
    }

    float lp_r = step0 ? 0.0f : lp[row];
    int   f    = step0 ? 0    : fin[row];
    if (step0 && j != 0) {
        if (tid < 4) { rcv[row * 4 + tid] = NEGF; rci[row * 4 + tid] = base_idx + tid; }
        return;
    }
    if (f) {
        if (tid < 4) {
            rcv[row * 4 + tid] = (tid == 0) ? lp_r : NEGF;
            rci[row * 4 + tid] = base_idx + tid;
        }
        return;
    }

    red[tid] = m; __syncthreads();
    for (int s = 512; s > 0; s >>= 1) {
        if (tid < s) red[tid] = fmax(red[tid], red[tid + s]);
        __syncthreads();
    }
    m = red[0];
    __syncthreads();

    // ---- pass 2: sumexp from registers
    double sum = 0.0;
    #pragma unroll
    for (int q = 0; q < NPT; q++) {
        int i = tid + q * 1024;
        if (i < VV) sum += exp((double)zreg[q] - m);
    }
    red[tid] = sum; __syncthreads();
    for (int s = 512; s > 0; s >>= 1) {
        if (tid < s) red[tid] += red[tid + s];
        __syncthreads();
    }
    double lse = m + log(red[0]);
    __syncthreads();

    // ---- pass 3: per-thread top-4 from registers
    float bv[4]; int bx[4];
    #pragma unroll
    for (int q = 0; q < 4; q++) { bv[q] = -3.4e38f; bx[q] = 0x7fffffff; }
    #pragma unroll
    for (int q = 0; q < NPT; q++) {
        int i = tid + q * 1024;
        if (i < VV) {
            float lgp32 = (float)((double)zreg[q] - lse);
            float val   = (float)((double)lp_r + (double)lgp32);
            int idx = base_idx + i;
            if (better(val, idx, bv[3], bx[3])) {
                bv[3] = val; bx[3] = idx;
                #pragma unroll
                for (int s = 3; s > 0; s--) {
                    if (better(bv[s], bx[s], bv[s - 1], bx[s - 1])) {
                        float tv2 = bv[s]; bv[s] = bv[s - 1]; bv[s - 1] = tv2;
                        int ti2 = bx[s]; bx[s] = bx[s - 1]; bx[s - 1] = ti2;
                    }
                }
            }
        }
    }

    __shared__ float sv[1024][4];
    __shared__ int   si_[1024][4];
    #pragma unroll
    for (int q = 0; q < 4; q++) { sv[tid][q] = bv[q]; si_[tid][q] = bx[q]; }
    __syncthreads();
    for (int s = 512; s > 0; s >>= 1) {
        if (tid < s) {
            float av[4], ov[4], mv[4]; int ai[4], oi[4], mi[4];
            #pragma unroll
            for (int q = 0; q < 4; q++) {
                av[q] = sv[tid][q];     ai[q] = si_[tid][q];
                ov[q] = sv[tid + s][q]; oi[q] = si_[tid + s][q];
            }
            int pa = 0, pb = 0;
            #pragma unroll
            for (int q = 0; q < 4; q++) {
                bool takeA = (pb >= 4) || (pa < 4 && better(av[pa], ai[pa], ov[pb], oi[pb]));
                if (takeA) { mv[q] = av[pa]; mi[q] = ai[pa]; pa++; }
                else       { mv[q] = ov[pb]; mi[q] = oi[pb]; pb++; }
            }
            #pragma unroll
            for (int q = 0; q < 4; q++) { sv[tid][q] = mv[q]; si_[tid][q] = mi[q]; }
        }
        __syncthreads();
    }
    if (tid < 4) {
        rcv[row * 4 + tid] = sv[0][tid];
        rci[row * 4 + tid] = si_[0][tid];
    }
}

// ---------------------------------------------------------------- merge 16 candidates/batch + state update
__global__ void merge_update_kernel(
    const float* __restrict__ rcv, const int* __restrict__ rci,
    float* __restrict__ lp, int* __restrict__ fin,
    int* __restrict__ tokens, int* __restrict__ pidx,
    int* __restrict__ bo, int t)
{
    int b = threadIdx.x;           // 64
    int bi = b >> 2, r = b & 3;

    float cv[16]; int ci[16];
    #pragma unroll
    for (int c = 0; c < 16; c++) { cv[c] = rcv[bi * 16 + c]; ci[c] = rci[bi * 16 + c]; }

    int sel = 0;
    #pragma unroll
    for (int c = 0; c < 16; c++) {
        int rank = 0;
        #pragma unroll
        for (int d = 0; d < 16; d++)
            if (d != c && better(cv[d], ci[d], cv[c], ci[c])) rank++;
        if (rank == r) sel = c;
    }

    float v = cv[sel];
    int flat = ci[sel];
    int q = flat / VV;
    int p = q + bi * 4;
    int tok = flat - q * VV;
    int oldfin = fin[p];
    int col[TSTEPS + 1];
    #pragma unroll
    for (int rr = 0; rr <= TSTEPS; rr++) col[rr] = bo[rr * BB + p];
    __syncthreads();
    #pragma unroll
    for (int rr = 0; rr <= TSTEPS; rr++) bo[rr * BB + b] = col[rr];
    bo[(t + 1) * BB + b] = tok;
    fin[b]    = oldfin | (tok == EOSTOK);
    lp[b]     = v;
    tokens[b] = tok;
    pidx[b]   = p;
}

// ---------------------------------------------------------------- final beam_out -> float
__global__ void final_kernel(const int* __restrict__ bo, float* __restrict__ out)
{
    int i = blockIdx.x * blockDim.x + threadIdx.x;
    if (i < (TSTEPS + 1) * BB) out[i] = (float)bo[i];
}

// ---------------------------------------------------------------- host
extern "C" void kernel_launch(void* const* d_in, const int* in_sizes, int n_in,
                              void* d_out, int out_size, void* d_ws, size_t ws_size,
                              hipStream_t stream)
{
    const int*   inputs = (const int*)d_in[0];
    const float* h0   = (const float*)d_in[1];
    const float* c0   = (const float*)d_in[2];
    const float* emb  = (const float*)d_in[3];
    const float* Wih0 = (const float*)d_in[4];
    const float* Whh0 = (const float*)d_in[5];
    const float* b0   = (const float*)d_in[6];
    const float* Wih1 = (const float*)d_in[7];
    const float* Whh1 = (const float*)d_in[8];
    const float* b1   = (const float*)d_in[9];
    const float* Wp   = (const float*)d_in[10];
    const float* bp   = (const float*)d_in[11];
    float* out = (float*)d_out;

    char* w = (char*)d_ws;
    size_t off = 0;
    auto alloc = [&](size_t bytes) { void* p = w + off; off += (bytes + 255) & ~255ULL; return p; };
    double* pp = (double*)alloc((size_t)2 * BB * VV * 8);   // fp64 K-split partials
    float* h0s[2], *c0s[2], *h1s[2], *c1s[2];
    for (int s = 0; s < 2; s++) {
        h0s[s] = (float*)alloc(BB * DD * 4);
        c0s[s] = (float*)alloc(BB * DD * 4);
        h1s[s] = (float*)alloc(BB * DD * 4);
        c1s[s] = (float*)alloc(BB * DD * 4);
    }
    float* rcv   = (float*)alloc(BB * 4 * 4);
    int*   rci   = (int*)alloc(BB * 4 * 4);
    float* lp    = (float*)alloc(BB * 4);
    int* pidx    = (int*)alloc(BB * 4);
    int* tokens  = (int*)alloc(BB * 4);
    int* fin     = (int*)alloc(BB * 4);
    int* bo      = (int*)alloc((TSTEPS + 1) * BB * 4);

    init_kernel<<<128, 256, 0, stream>>>(inputs, h0, c0,
                                         h0s[0], c0s[0], h1s[0], c1s[0],
                                         tokens, pidx, fin, lp, bo);

    for (int t = 0; t < TSTEPS; t++) {
        int s = t & 1, d2 = s ^ 1;
        lstm_kernel<<<512, 256, 0, stream>>>(emb, tokens, h0s[s], c0s[s], pidx,
                                             h0s[d2], c0s[d2], Wih0, Whh0, b0);
        lstm_kernel<<<512, 256, 0, stream>>>(h0s[d2], nullptr, h1s[s], c1s[s], pidx,
                                             h1s[d2], c1s[d2], Wih1, Whh1, b1);

        float* outf = out + (size_t)t * BB * VV;
        proj_kernel<<<NVT * 2, 256, 0, stream>>>(h1s[d2], Wp, pp);
        row_kernel<<<BB, 1024, 0, stream>>>(pp, bp, outf, lp, fin, rcv, rci, t == 0 ? 1 : 0);
        merge_update_kernel<<<1, 64, 0, stream>>>(rcv, rci, lp, fin, tokens, pidx, bo, t);
    }
    final_kernel<<<5, 256, 0, stream>>>(bo, out + (size_t)TSTEPS * BB * VV);
}

// Round 13
// 2851.061 us; speedup vs baseline: 11.2240x; 1.0737x over previous
//
#include <hip/hip_runtime.h>
#include <math.h>

#define BS     16
#define NB     4
#define BB     64      // BS*NB
#define DD     512
#define VV     32000
#define TSTEPS 16
#define EOSTOK 2
#define NEGF   (-1e32f)
#define VT     64
#define NVT    (VV / VT)   // 500

__device__ __forceinline__ bool better(float av, int ai, float bv, int bi_) {
    return (av > bv) || (av == bv && ai < bi_);
}

// async global->LDS staging, no VGPR round-trip (gfx950)
__device__ __forceinline__ void glds4(const float* src, float* dst) {
    __builtin_amdgcn_global_load_lds((const __attribute__((address_space(1))) void*)src,
                                     (__attribute__((address_space(3))) void*)dst, 4, 0, 0);
}
__device__ __forceinline__ void glds16(const float* src, float* dst) {
    __builtin_amdgcn_global_load_lds((const __attribute__((address_space(1))) void*)src,
                                     (__attribute__((address_space(3))) void*)dst, 16, 0, 0);
}

// ---------------------------------------------------------------- init (fp32 states)
__global__ void init_kernel(const int* __restrict__ inputs,
                            const float* __restrict__ h0, const float* __restrict__ c0,
                            float* __restrict__ h0s, float* __restrict__ c0s,
                            float* __restrict__ h1s, float* __restrict__ c1s,
                            int* __restrict__ tokens, int* __restrict__ pidx,
                            int* __restrict__ fin, float* __restrict__ lp,
                            int* __restrict__ bo)
{
    int tid = blockIdx.x * blockDim.x + threadIdx.x;
    int total = BB * DD;
    for (int i = tid; i < total; i += gridDim.x * blockDim.x) {
        int b = i / DD;
        int d = i % DD;
        int src0 = 0 * BS * DD + (b >> 2) * DD + d;
        int src1 = 1 * BS * DD + (b >> 2) * DD + d;
        h0s[i] = h0[src0];
        c0s[i] = c0[src0];
        h1s[i] = h0[src1];
        c1s[i] = c0[src1];
    }
    if (tid < BB) {
        tokens[tid] = inputs[tid >> 2];
        pidx[tid]   = tid;
        fin[tid]    = 0;
        lp[tid]     = 0.0f;
        bo[0 * BB + tid] = inputs[tid >> 2];
        for (int r = 1; r <= TSTEPS; r++) bo[r * BB + tid] = 0;
    }
}

// ---------------------------------------------------------------- LSTM: one block per output unit j
// 512 blocks x 256 threads; thread = (b 0..63, gate 0..3). Staging via global_load_lds.
// FMA order bitwise-identical to the passing R12 kernel.
__global__ __launch_bounds__(256) void lstm_kernel(
    const float* __restrict__ xbase, const int* __restrict__ xrow,
    const float* __restrict__ hsrc,  const float* __restrict__ csrc,
    const int* __restrict__ prow,
    float* __restrict__ hdst, float* __restrict__ cdst,
    const float* __restrict__ Wih, const float* __restrict__ Whh,
    const float* __restrict__ bias)
{
    __shared__ float U[64][129];    // [b][k]: bank (b+k)%32; each wave-instr writes 256B inside one row
    __shared__ float Wl[4][1024];   // all weight rows for this j (16 KB), contiguous
    __shared__ double Z[4][64];
    __shared__ int rows_s[64], prows_s[64];
    int tid = threadIdx.x;
    int j = blockIdx.x;
    int b = tid & 63;
    int g = tid >> 6;
    int lane = tid & 63;
    int w = tid >> 6;               // wave id 0..3

    // ---- W burst: 16 KB via width-16 async copies (4 per thread), fully concurrent
    #pragma unroll
    for (int i = 0; i < 4; i++) {
        int s0 = i * 256 + w * 64;              // wave-uniform float4 slot base (0..1023)
        int gg = s0 >> 8;                       // gate
        int hh = (s0 >> 7) & 1;                 // 0 = Wih half, 1 = Whh half
        int c0 = s0 & 127;                      // float4 col within the 512-float row
        const float* rowbase = (hh ? Whh : Wih) + (size_t)(gg * DD + j) * DD;
        glds16(rowbase + 4 * (c0 + lane), (float*)Wl + 4 * s0);
    }
    if (tid < 64) {
        rows_s[tid]  = xrow ? xrow[tid] : tid;
        prows_s[tid] = prow[tid];
    }

    double a0 = 0.0, a1 = 0.0, a2 = 0.0, a3 = 0.0;   // ILP-4 chains (kk%4)
    for (int ch = 0; ch < 8; ch++) {
        int k0 = ch * 128;
        __syncthreads();    // prev chunk's readers done; rows_s visible (first iter)
        #pragma unroll
        for (int i = 0; i < 32; i++) {          // async U stage: 64x128, 256B per wave-instr
            int e0 = i * 256 + w * 64;          // wave-uniform
            int bb = e0 >> 7;                   // row (constant per wave-instr)
            int kk0 = e0 & 127;                 // 0 or 64
            const float* src;
            if (k0 < 512) src = xbase + (size_t)rows_s[bb] * DD + k0 + kk0 + lane;
            else          src = hsrc + (size_t)prows_s[bb] * DD + (k0 - 512) + kk0 + lane;
            glds4(src, &U[bb][kk0]);
        }
        __syncthreads();    // vmcnt drained before barrier -> LDS writes landed
        const float* Wrow = &Wl[g][k0];         // wave-uniform broadcast reads
        #pragma unroll 8
        for (int kk = 0; kk < 128; kk += 4) {
            a0 = fma((double)U[b][kk + 0], (double)Wrow[kk + 0], a0);
            a1 = fma((double)U[b][kk + 1], (double)Wrow[kk + 1], a1);
            a2 = fma((double)U[b][kk + 2], (double)Wrow[kk + 2], a2);
            a3 = fma((double)U[b][kk + 3], (double)Wrow[kk + 3], a3);
        }
    }
    Z[g][b] = ((a0 + a1) + (a2 + a3));
    __syncthreads();

    if (tid < 64) {
        double zi = Z[0][b] + (double)bias[0 * DD + j];
        double zf = Z[1][b] + (double)bias[1 * DD + j];
        double zg = Z[2][b] + (double)bias[2 * DD + j];
        double zo = Z[3][b] + (double)bias[3 * DD + j];
        double si = 1.0 / (1.0 + exp(-zi));
        double sf = 1.0 / (1.0 + exp(-zf));
        double so = 1.0 / (1.0 + exp(-zo));
        double cold = (double)csrc[(size_t)prows_s[b] * DD + j];
        double cn = sf * cold + si * tanh(zg);
        double hn = so * tanh(cn);
        hdst[b * DD + j] = (float)hn;   // fp32 boundary
        cdst[b * DD + j] = (float)cn;
    }
}

// ---------------------------------------------------------------- projection GEMM, full K
// grid NVT=500 blocks, 256 threads, thread tile 4b x 4v, fp64 acc over K=512,
// writes fp32 logits (+bias) directly. No partial buffer.
__global__ __launch_bounds__(256) void proj_kernel(
    const float* __restrict__ h1, const float* __restrict__ Wp,
    const float* __restrict__ bp, float* __restrict__ outf)
{
    __shared__ float sh[64][68];    // [b][k-chunk]
    __shared__ float sw[64][68];    // [k-chunk][v]
    int vbase = blockIdx.x * VT;
    int tid = threadIdx.x;
    int lane = tid & 63;
    int w = tid >> 6;
    int b0 = (tid >> 4) * 4;
    int v0 = (tid & 15) * 4;

    double acc[4][4];
    #pragma unroll
    for (int i = 0; i < 4; i++)
        #pragma unroll
        for (int q = 0; q < 4; q++) acc[i][q] = 0.0;

    for (int ch = 0; ch < 8; ch++) {
        int k0 = ch * 64;
        __syncthreads();
        #pragma unroll
        for (int i = 0; i < 16; i++) {          // sh: row bb = i*4+w, cols 0..63
            int bb = i * 4 + w;
            glds4(h1 + (size_t)bb * DD + k0 + lane, &sh[bb][0]);
        }
        #pragma unroll
        for (int i = 0; i < 16; i++) {          // sw: row kk = i*4+w, cols 0..63
            int kk = i * 4 + w;
            glds4(Wp + (size_t)(k0 + kk) * VV + vbase + lane, &sw[kk][0]);
        }
        __syncthreads();
        #pragma unroll
        for (int k4 = 0; k4 < 16; k4++) {
            int k = k4 * 4;
            float4 h4[4], w4[4];
            #pragma unroll
            for (int i = 0; i < 4; i++) h4[i] = *(const float4*)&sh[b0 + i][k];
            #pragma unroll
            for (int kk = 0; kk < 4; kk++) w4[kk] = *(const float4*)&sw[k + kk][v0];
            #pragma unroll
            for (int i = 0; i < 4; i++) {
                const float hh[4] = {h4[i].x, h4[i].y, h4[i].z, h4[i].w};
                #pragma unroll
                for (int kk = 0; kk < 4; kk++) {
                    double hd = (double)hh[kk];
                    const float ww[4] = {w4[kk].x, w4[kk].y, w4[kk].z, w4[kk].w};
                    #pragma unroll
                    for (int q = 0; q < 4; q++)
                        acc[i][q] = fma(hd, (double)ww[q], acc[i][q]);
                }
            }
        }
    }

    #pragma unroll
    for (int i = 0; i < 4; i++) {
        int brow = b0 + i;
        #pragma unroll
        for (int q = 0; q < 4; q++) {
            int v = vbase + v0 + q;
            outf[(size_t)brow * VV + v] = (float)(acc[i][q] + (double)bp[v]);  // fp32 boundary
        }
    }
}

// ---------------------------------------------------------------- fused LSE + row top-4 (fp32 logits in)
#define NPT 32   // ceil(32000/1024)
__global__ __launch_bounds__(1024) void row_kernel(
    const float* __restrict__ outf, const float* __restrict__ lp,
    const int* __restrict__ fin,
    float* __restrict__ rcv, int* __restrict__ rci, int step0)
{
    int row = blockIdx.x;
    int j   = row & 3;
    int tid = threadIdx.x;
    int base_idx = j * VV;

    float lp_r = step0 ? 0.0f : lp[row];
    int   f    = step0 ? 0    : fin[row];
    if (step0 && j != 0) {
        if (tid < 4) { rcv[row * 4 + tid] = NEGF; rci[row * 4 + tid] = base_idx + tid; }
        return;
    }
    if (f) {
        if (tid < 4) {
            rcv[row * 4 + tid] = (tid == 0) ? lp_r : NEGF;
            rci[row * 4 + tid] = base_idx + tid;
        }
        return;
    }

    const float* xo = outf + (size_t)row * VV;
    __shared__ double red[1024];

    // ---- pass 1: load fp32 logits, cache in regs, max
    float zreg[NPT];
    double m = -1e300;
    #pragma unroll
    for (int q = 0; q < NPT; q++) {
        int i = tid + q * 1024;
        float zf = 0.0f;
        if (i < VV) {
            zf = xo[i];
            m = fmax(m, (double)zf);
        }
        zreg[q] = zf;
    }

    red[tid] = m; __syncthreads();
    for (int s = 512; s > 0; s >>= 1) {
        if (tid < s) red[tid] = fmax(red[tid], red[tid + s]);
        __syncthreads();
    }
    m = red[0];
    __syncthreads();

    // ---- pass 2: sumexp from registers
    double sum = 0.0;
    #pragma unroll
    for (int q = 0; q < NPT; q++) {
        int i = tid + q * 1024;
        if (i < VV) sum += exp((double)zreg[q] - m);
    }
    red[tid] = sum; __syncthreads();
    for (int s = 512; s > 0; s >>= 1) {
        if (tid < s) red[tid] += red[tid + s];
        __syncthreads();
    }
    double lse = m + log(red[0]);
    __syncthreads();

    // ---- pass 3: per-thread top-4 from registers
    float bv[4]; int bx[4];
    #pragma unroll
    for (int q = 0; q < 4; q++) { bv[q] = -3.4e38f; bx[q] = 0x7fffffff; }
    #pragma unroll
    for (int q = 0; q < NPT; q++) {
        int i = tid + q * 1024;
        if (i < VV) {
            float lgp32 = (float)((double)zreg[q] - lse);
            float val   = (float)((double)lp_r + (double)lgp32);
            int idx = base_idx + i;
            if (better(val, idx, bv[3], bx[3])) {
                bv[3] = val; bx[3] = idx;
                #pragma unroll
                for (int s = 3; s > 0; s--) {
                    if (better(bv[s], bx[s], bv[s - 1], bx[s - 1])) {
                        float tv2 = bv[s]; bv[s] = bv[s - 1]; bv[s - 1] = tv2;
                        int ti2 = bx[s]; bx[s] = bx[s - 1]; bx[s - 1] = ti2;
                    }
                }
            }
        }
    }

    __shared__ float sv[1024][4];
    __shared__ int   si_[1024][4];
    #pragma unroll
    for (int q = 0; q < 4; q++) { sv[tid][q] = bv[q]; si_[tid][q] = bx[q]; }
    __syncthreads();
    for (int s = 512; s > 0; s >>= 1) {
        if (tid < s) {
            float av[4], ov[4], mv[4]; int ai[4], oi[4], mi[4];
            #pragma unroll
            for (int q = 0; q < 4; q++) {
                av[q] = sv[tid][q];     ai[q] = si_[tid][q];
                ov[q] = sv[tid + s][q]; oi[q] = si_[tid + s][q];
            }
            int pa = 0, pb = 0;
            #pragma unroll
            for (int q = 0; q < 4; q++) {
                bool takeA = (pb >= 4) || (pa < 4 && better(av[pa], ai[pa], ov[pb], oi[pb]));
                if (takeA) { mv[q] = av[pa]; mi[q] = ai[pa]; pa++; }
                else       { mv[q] = ov[pb]; mi[q] = oi[pb]; pb++; }
            }
            #pragma unroll
            for (int q = 0; q < 4; q++) { sv[tid][q] = mv[q]; si_[tid][q] = mi[q]; }
        }
        __syncthreads();
    }
    if (tid < 4) {
        rcv[row * 4 + tid] = sv[0][tid];
        rci[row * 4 + tid] = si_[0][tid];
    }
}

// ---------------------------------------------------------------- merge 16 candidates/batch + state update
__global__ void merge_update_kernel(
    const float* __restrict__ rcv, const int* __restrict__ rci,
    float* __restrict__ lp, int* __restrict__ fin,
    int* __restrict__ tokens, int* __restrict__ pidx,
    int* __restrict__ bo, int t)
{
    int b = threadIdx.x;           // 64
    int bi = b >> 2, r = b & 3;

    float cv[16]; int ci[16];
    #pragma unroll
    for (int c = 0; c < 16; c++) { cv[c] = rcv[bi * 16 + c]; ci[c] = rci[bi * 16 + c]; }

    int sel = 0;
    #pragma unroll
    for (int c = 0; c < 16; c++) {
        int rank = 0;
        #pragma unroll
        for (int d = 0; d < 16; d++)
            if (d != c && better(cv[d], ci[d], cv[c], ci[c])) rank++;
        if (rank == r) sel = c;
    }

    float v = cv[sel];
    int flat = ci[sel];
    int q = flat / VV;
    int p = q + bi * 4;
    int tok = flat - q * VV;
    int oldfin = fin[p];
    int col[TSTEPS + 1];
    #pragma unroll
    for (int rr = 0; rr <= TSTEPS; rr++) col[rr] = bo[rr * BB + p];
    __syncthreads();
    #pragma unroll
    for (int rr = 0; rr <= TSTEPS; rr++) bo[rr * BB + b] = col[rr];
    bo[(t + 1) * BB + b] = tok;
    fin[b]    = oldfin | (tok == EOSTOK);
    lp[b]     = v;
    tokens[b] = tok;
    pidx[b]   = p;
}

// ---------------------------------------------------------------- final beam_out -> float
__global__ void final_kernel(const int* __restrict__ bo, float* __restrict__ out)
{
    int i = blockIdx.x * blockDim.x + threadIdx.x;
    if (i < (TSTEPS + 1) * BB) out[i] = (float)bo[i];
}

// ---------------------------------------------------------------- host
extern "C" void kernel_launch(void* const* d_in, const int* in_sizes, int n_in,
                              void* d_out, int out_size, void* d_ws, size_t ws_size,
                              hipStream_t stream)
{
    const int*   inputs = (const int*)d_in[0];
    const float* h0   = (const float*)d_in[1];
    const float* c0   = (const float*)d_in[2];
    const float* emb  = (const float*)d_in[3];
    const float* Wih0 = (const float*)d_in[4];
    const float* Whh0 = (const float*)d_in[5];
    const float* b0   = (const float*)d_in[6];
    const float* Wih1 = (const float*)d_in[7];
    const float* Whh1 = (const float*)d_in[8];
    const float* b1   = (const float*)d_in[9];
    const float* Wp   = (const float*)d_in[10];
    const float* bp   = (const float*)d_in[11];
    float* out = (float*)d_out;

    char* w = (char*)d_ws;
    size_t off = 0;
    auto alloc = [&](size_t bytes) { void* p = w + off; off += (bytes + 255) & ~255ULL; return p; };
    float* h0s[2], *c0s[2], *h1s[2], *c1s[2];
    for (int s = 0; s < 2; s++) {
        h0s[s] = (float*)alloc(BB * DD * 4);
        c0s[s] = (float*)alloc(BB * DD * 4);
        h1s[s] = (float*)alloc(BB * DD * 4);
        c1s[s] = (float*)alloc(BB * DD * 4);
    }
    float* rcv   = (float*)alloc(BB * 4 * 4);
    int*   rci   = (int*)alloc(BB * 4 * 4);
    float* lp    = (float*)alloc(BB * 4);
    int* pidx    = (int*)alloc(BB * 4);
    int* tokens  = (int*)alloc(BB * 4);
    int* fin     = (int*)alloc(BB * 4);
    int* bo      = (int*)alloc((TSTEPS + 1) * BB * 4);

    init_kernel<<<128, 256, 0, stream>>>(inputs, h0, c0,
                                         h0s[0], c0s[0], h1s[0], c1s[0],
                                         tokens, pidx, fin, lp, bo);

    for (int t = 0; t < TSTEPS; t++) {
        int s = t & 1, d2 = s ^ 1;
        lstm_kernel<<<512, 256, 0, stream>>>(emb, tokens, h0s[s], c0s[s], pidx,
                                             h0s[d2], c0s[d2], Wih0, Whh0, b0);
        lstm_kernel<<<512, 256, 0, stream>>>(h0s[d2], nullptr, h1s[s], c1s[s], pidx,
                                             h1s[d2], c1s[d2], Wih1, Whh1, b1);

        float* outf = out + (size_t)t * BB * VV;
        proj_kernel<<<NVT, 256, 0, stream>>>(h1s[d2], Wp, bp, outf);
        row_kernel<<<BB, 1024, 0, stream>>>(outf, lp, fin, rcv, rci, t == 0 ? 1 : 0);
        merge_update_kernel<<<1, 64, 0, stream>>>(rcv, rci, lp, fin, tokens, pidx, bo, t);
    }
    final_kernel<<<5, 256, 0, stream>>>(bo, out + (size_t)TSTEPS * BB * VV);
}